// Round 1
// baseline (101698.920 us; speedup 1.0000x reference)
//
#include <hip/hip_runtime.h>
#include <math.h>

#define N_ 64
#define T_ 256
#define I_ 512
#define H_ 1024

__device__ __forceinline__ float sigmoidf_(float v) {
    return 1.0f / (1.0f + __expf(-v));
}

__global__ __launch_bounds__(256) void init_state(
    const float* __restrict__ hx, const float* __restrict__ cx,
    float* __restrict__ h, float* __restrict__ c)
{
    int idx = blockIdx.x * 256 + threadIdx.x;  // N_*H_ = 65536 total
    int m = idx >> 10;          // / H_
    int j = idx & (H_ - 1);     // % H_
    // hx, cx are (N, T, H); take [:, 0, :]
    h[idx] = hx[(size_t)m * T_ * H_ + j];
    c[idx] = cx[(size_t)m * T_ * H_ + j];
}

// One step of the LSTM scan. Grid: (4 j-groups, 64 batch). 256 threads.
// Each thread owns one hidden unit j for one batch m: computes the 4 gate
// dot-products (K = I_ + H_ = 1536) against LDS-staged [x_t ; h*r].
__global__ __launch_bounds__(256) void lstm_step(
    const float* __restrict__ x, const int* __restrict__ is_init,
    const float* __restrict__ W_ih, const float* __restrict__ W_hh,
    const float* __restrict__ b_ih, const float* __restrict__ b_hh,
    const float* __restrict__ h_in, float* __restrict__ h_out,
    float* __restrict__ c, float* __restrict__ hs, int t)
{
    __shared__ float z[I_ + H_];   // [x_t (512) ; h*r (1024)]
    const int m   = blockIdx.y;
    const int tid = threadIdx.x;

    const float r = (is_init[m * T_ + t] != 0) ? 0.0f : 1.0f;

    const float* xrow = x + ((size_t)m * T_ + t) * I_;
    for (int k = tid; k < I_; k += 256) z[k] = xrow[k];
    for (int k = tid; k < H_; k += 256) z[I_ + k] = h_in[m * H_ + k] * r;
    __syncthreads();

    const int j = blockIdx.x * 256 + tid;

    float a0 = 0.f, a1 = 0.f, a2 = 0.f, a3 = 0.f;

    // x-part: K = 512
    {
        const float4* zv = (const float4*)z;
        const float4* w0 = (const float4*)(W_ih + (size_t)(0 * H_ + j) * I_);
        const float4* w1 = (const float4*)(W_ih + (size_t)(1 * H_ + j) * I_);
        const float4* w2 = (const float4*)(W_ih + (size_t)(2 * H_ + j) * I_);
        const float4* w3 = (const float4*)(W_ih + (size_t)(3 * H_ + j) * I_);
        #pragma unroll 4
        for (int k = 0; k < I_ / 4; ++k) {
            float4 s = zv[k];
            float4 a = w0[k]; a0 += a.x*s.x + a.y*s.y + a.z*s.z + a.w*s.w;
            float4 b = w1[k]; a1 += b.x*s.x + b.y*s.y + b.z*s.z + b.w*s.w;
            float4 d = w2[k]; a2 += d.x*s.x + d.y*s.y + d.z*s.z + d.w*s.w;
            float4 e = w3[k]; a3 += e.x*s.x + e.y*s.y + e.z*s.z + e.w*s.w;
        }
    }
    // h-part: K = 1024
    {
        const float4* zv = (const float4*)(z + I_);
        const float4* w0 = (const float4*)(W_hh + (size_t)(0 * H_ + j) * H_);
        const float4* w1 = (const float4*)(W_hh + (size_t)(1 * H_ + j) * H_);
        const float4* w2 = (const float4*)(W_hh + (size_t)(2 * H_ + j) * H_);
        const float4* w3 = (const float4*)(W_hh + (size_t)(3 * H_ + j) * H_);
        #pragma unroll 4
        for (int k = 0; k < H_ / 4; ++k) {
            float4 s = zv[k];
            float4 a = w0[k]; a0 += a.x*s.x + a.y*s.y + a.z*s.z + a.w*s.w;
            float4 b = w1[k]; a1 += b.x*s.x + b.y*s.y + b.z*s.z + b.w*s.w;
            float4 d = w2[k]; a2 += d.x*s.x + d.y*s.y + d.z*s.z + d.w*s.w;
            float4 e = w3[k]; a3 += e.x*s.x + e.y*s.y + e.z*s.z + e.w*s.w;
        }
    }

    // gate order from jnp.split: i, f, g, o
    float i_g = a0 + b_ih[0 * H_ + j] + b_hh[0 * H_ + j];
    float f_g = a1 + b_ih[1 * H_ + j] + b_hh[1 * H_ + j];
    float g_g = a2 + b_ih[2 * H_ + j] + b_hh[2 * H_ + j];
    float o_g = a3 + b_ih[3 * H_ + j] + b_hh[3 * H_ + j];

    float ce = c[m * H_ + j] * r;
    float cn = sigmoidf_(f_g) * ce + sigmoidf_(i_g) * tanhf(g_g);
    float hn = sigmoidf_(o_g) * tanhf(cn);

    c[m * H_ + j]     = cn;
    h_out[m * H_ + j] = hn;
    hs[((size_t)m * T_ + t) * H_ + j] = hn;
}

// out0[m,t,:] = mish(hs[m,t,:] @ W_out^T + b_out). Grid: (T, N), 256 threads,
// each thread computes 4 output dims.
__global__ __launch_bounds__(256) void out_proj(
    const float* __restrict__ hs, const float* __restrict__ W_out,
    const float* __restrict__ b_out, float* __restrict__ out0)
{
    __shared__ float hrow[H_];
    const int t = blockIdx.x, m = blockIdx.y, tid = threadIdx.x;

    const float* src = hs + ((size_t)m * T_ + t) * H_;
    for (int k = tid; k < H_; k += 256) hrow[k] = src[k];
    __syncthreads();

    const float4* hv = (const float4*)hrow;
    #pragma unroll
    for (int q = 0; q < 4; ++q) {
        const int jo = q * 256 + tid;
        const float4* w = (const float4*)(W_out + (size_t)jo * H_);
        float acc = 0.f;
        #pragma unroll 4
        for (int k = 0; k < H_ / 4; ++k) {
            float4 s = hv[k];
            float4 a = w[k];
            acc += a.x*s.x + a.y*s.y + a.z*s.z + a.w*s.w;
        }
        float y  = acc + b_out[jo];
        float sp = (y > 0.f) ? (y + log1pf(__expf(-y))) : log1pf(__expf(y));
        out0[((size_t)m * T_ + t) * H_ + jo] = y * tanhf(sp);
    }
}

__global__ __launch_bounds__(256) void bcast_hc(
    const float* __restrict__ hf, const float* __restrict__ cf,
    float* __restrict__ out1, float* __restrict__ out2)
{
    const size_t total = (size_t)N_ * T_ * H_;
    for (size_t idx = (size_t)blockIdx.x * 256 + threadIdx.x; idx < total;
         idx += (size_t)gridDim.x * 256) {
        int m = (int)(idx / ((size_t)T_ * H_));
        int j = (int)(idx & (H_ - 1));
        out1[idx] = hf[m * H_ + j];
        out2[idx] = cf[m * H_ + j];
    }
}

extern "C" void kernel_launch(void* const* d_in, const int* in_sizes, int n_in,
                              void* d_out, int out_size, void* d_ws, size_t ws_size,
                              hipStream_t stream) {
    const float* x      = (const float*)d_in[0];
    const int*   is_ini = (const int*)  d_in[1];
    const float* hx     = (const float*)d_in[2];
    const float* cx     = (const float*)d_in[3];
    const float* W_ih   = (const float*)d_in[4];
    const float* W_hh   = (const float*)d_in[5];
    const float* b_ih   = (const float*)d_in[6];
    const float* b_hh   = (const float*)d_in[7];
    const float* W_out  = (const float*)d_in[8];
    const float* b_out  = (const float*)d_in[9];

    float* out0 = (float*)d_out;
    float* out1 = out0 + (size_t)N_ * T_ * H_;
    float* out2 = out1 + (size_t)N_ * T_ * H_;

    float* ws = (float*)d_ws;
    float* h0 = ws;                 // 64*1024
    float* h1 = ws + N_ * H_;       // 64*1024
    float* c  = ws + 2 * N_ * H_;   // 64*1024

    init_state<<<N_ * H_ / 256, 256, 0, stream>>>(hx, cx, h0, c);

    float* hs = out1;  // temporarily store hs in the out1 region (same layout)
    for (int t = 0; t < T_; ++t) {
        const float* hin = (t & 1) ? h1 : h0;
        float*       hout = (t & 1) ? h0 : h1;
        lstm_step<<<dim3(H_ / 256, N_), 256, 0, stream>>>(
            x, is_ini, W_ih, W_hh, b_ih, b_hh, hin, hout, c, hs, t);
    }

    out_proj<<<dim3(T_, N_), 256, 0, stream>>>(hs, W_out, b_out, out0);

    // final h landed in h0 (t=255 odd wrote h0); c is in-place
    bcast_hc<<<2048, 256, 0, stream>>>(h0, c, out1, out2);
}

// Round 2
// 8741.451 us; speedup vs baseline: 11.6341x; 11.6341x over previous
//
#include <hip/hip_runtime.h>
#include <math.h>

#define N_ 64
#define T_ 256
#define I_ 512
#define H_ 1024

typedef unsigned short u16;
typedef short bf16x8 __attribute__((ext_vector_type(8)));
typedef float f32x4 __attribute__((ext_vector_type(4)));

__device__ __forceinline__ u16 f2bf(float f) {
    union { float f; unsigned int u; } x; x.f = f;
    unsigned int r = (x.u + 0x7FFFu + ((x.u >> 16) & 1u)) >> 16;
    return (u16)r;
}
__device__ __forceinline__ float bf2f(u16 u) {
    union { unsigned int u; float f; } x; x.u = ((unsigned int)u) << 16;
    return x.f;
}
__device__ __forceinline__ float sigmoidf_(float v) {
    return 1.0f / (1.0f + __expf(-v));
}

// ---------------- prep kernels ----------------

// Pack W rows: packed row rp = j*4+g holds [W_ih[g*1024+j][0:512] ; W_hh[g*1024+j][0:1024]] bf16.
__global__ __launch_bounds__(256) void pack_weights(
    const float* __restrict__ W_ih, const float* __restrict__ W_hh,
    const float* __restrict__ b_ih, const float* __restrict__ b_hh,
    u16* __restrict__ Wp, float* __restrict__ bp)
{
    const int rp = blockIdx.x;            // 0..4095
    const int j = rp >> 2, g = rp & 3;
    const int src = g * H_ + j;
    const float* wi = W_ih + (size_t)src * I_;
    const float* wh = W_hh + (size_t)src * H_;
    u16* dst = Wp + (size_t)rp * (I_ + H_);
    for (int k = threadIdx.x; k < I_; k += 256) dst[k] = f2bf(wi[k]);
    for (int k = threadIdx.x; k < H_; k += 256) dst[I_ + k] = f2bf(wh[k]);
    if (threadIdx.x == 0) bp[rp] = b_ih[src] + b_hh[src];
}

// x (N,T,I) fp32 -> x_tb (T,N,I) bf16
__global__ __launch_bounds__(256) void conv_x(
    const float* __restrict__ x, u16* __restrict__ x_tb)
{
    const int t = blockIdx.x, n = blockIdx.y;
    const float* s = x + ((size_t)n * T_ + t) * I_;
    u16* d = x_tb + ((size_t)t * N_ + n) * I_;
    for (int k = threadIdx.x; k < I_; k += 256) d[k] = f2bf(s[k]);
}

__global__ __launch_bounds__(256) void conv_wout(
    const float* __restrict__ W, u16* __restrict__ Wb)
{
    const size_t base = (size_t)blockIdx.x * 1024 + threadIdx.x;
    #pragma unroll
    for (int q = 0; q < 4; ++q) Wb[base + q * 256] = f2bf(W[base + q * 256]);
}

// h0 = bf16(hx[:,0]*r[:,0]) (pre-scaled); c = cx[:,0] (unscaled, scaled on read)
__global__ __launch_bounds__(256) void init_state2(
    const float* __restrict__ hx, const float* __restrict__ cx,
    const int* __restrict__ is_init, u16* __restrict__ h0, float* __restrict__ c_ws)
{
    const int idx = blockIdx.x * 256 + threadIdx.x;   // 65536
    const int n = idx >> 10, j = idx & (H_ - 1);
    const float r = (is_init[n * T_] != 0) ? 0.f : 1.f;
    h0[idx] = f2bf(hx[(size_t)n * T_ * H_ + j] * r);
    c_ws[idx] = cx[(size_t)n * T_ * H_ + j];
}

// ---------------- LSTM step (MFMA) ----------------
// Grid: 64 WGs x 256 thr. WG w owns hidden units w*16..w*16+15 (packed rows w*64..+63).
// Wave v: M-tile = packed rows w*64+v*16+0..15 (weights, first MFMA operand);
// N-tiles 0..3 = batches nt*16..nt*16+15 (z = [x_t ; h*r], second operand).
__global__ __launch_bounds__(256) void lstm_step_mfma(
    const u16* __restrict__ x_tb,    // [T][64][512]
    const u16* __restrict__ Wp,      // [4096][1536]
    const float* __restrict__ bp,    // [4096]
    const int* __restrict__ is_init, // [64][256]
    const u16* __restrict__ h_in,    // [64][1024]  (pre-scaled by r[t])
    u16* __restrict__ h_out,         // [64][1024]  (pre-scaled by r[t+1])
    float* __restrict__ c_ws,        // [64][1024]  (unscaled)
    u16* __restrict__ hs,            // [64][256][1024]  (unscaled)
    int t)
{
    const int w = blockIdx.x;
    const int tid = threadIdx.x;
    const int v = tid >> 6;
    const int l = tid & 63;
    const int l15 = l & 15, lh = l >> 4;

    const int base_m = w * 64 + v * 16;   // packed-row base for this wave

    const u16* wp  = Wp  + (size_t)(base_m + l15) * 1536 + lh * 8;
    const u16* xp0 = x_tb + ((size_t)t * N_ + l15) * I_ + lh * 8;
    const u16* hp0 = h_in + (size_t)l15 * H_ + lh * 8;

    f32x4 acc[4] = {f32x4{0,0,0,0}, f32x4{0,0,0,0}, f32x4{0,0,0,0}, f32x4{0,0,0,0}};

    // x part: K = 512 -> 16 k-steps
    #pragma unroll 4
    for (int kk = 0; kk < 16; ++kk) {
        bf16x8 wf = *(const bf16x8*)(wp + kk * 32);
        #pragma unroll
        for (int nt = 0; nt < 4; ++nt) {
            bf16x8 zf = *(const bf16x8*)(xp0 + (size_t)nt * 16 * I_ + kk * 32);
            acc[nt] = __builtin_amdgcn_mfma_f32_16x16x32_bf16(wf, zf, acc[nt], 0, 0, 0);
        }
    }
    // h part: K = 1024 -> 32 k-steps
    #pragma unroll 4
    for (int kk = 0; kk < 32; ++kk) {
        bf16x8 wf = *(const bf16x8*)(wp + I_ + kk * 32);
        #pragma unroll
        for (int nt = 0; nt < 4; ++nt) {
            bf16x8 zf = *(const bf16x8*)(hp0 + (size_t)nt * 16 * H_ + kk * 32);
            acc[nt] = __builtin_amdgcn_mfma_f32_16x16x32_bf16(wf, zf, acc[nt], 0, 0, 0);
        }
    }

    // Elementwise: lane l, N-tile nt -> batch n = nt*16 + l15;
    // unit j = base_m/4 + lh; gates i,f,g,o in acc[nt][0..3].
    const int j = (base_m >> 2) + lh;
    const float4 bias = *(const float4*)(bp + j * 4);

    #pragma unroll
    for (int nt = 0; nt < 4; ++nt) {
        const int n = nt * 16 + l15;
        const float rg = (is_init[n * T_ + t] != 0) ? 0.f : 1.f;
        const float rn = (t < T_ - 1) ? ((is_init[n * T_ + t + 1] != 0) ? 0.f : 1.f) : 1.f;

        const float i_g = acc[nt][0] + bias.x;
        const float f_g = acc[nt][1] + bias.y;
        const float g_g = acc[nt][2] + bias.z;
        const float o_g = acc[nt][3] + bias.w;

        const float cp = c_ws[n * H_ + j] * rg;
        const float cn = sigmoidf_(f_g) * cp + sigmoidf_(i_g) * tanhf(g_g);
        const float hv = sigmoidf_(o_g) * tanhf(cn);

        c_ws[n * H_ + j] = cn;
        hs[((size_t)n * T_ + t) * H_ + j] = f2bf(hv);
        h_out[n * H_ + j] = f2bf(hv * rn);
    }
}

// ---------------- output projection (MFMA GEMM + mish) ----------------
// out0[R][c] = mish(hs[R]·Wo[c] + b_out[c]),  R = n*T+t (16384 rows), K=N=1024.
// Grid (128,16): WG = 128 rows x 64 cols. Wave v: rows bx*128+v*32..+31 (2 M-tiles).
__global__ __launch_bounds__(256) void out_proj_mfma(
    const u16* __restrict__ hs, const u16* __restrict__ Wo,
    const float* __restrict__ b_out, float* __restrict__ out0)
{
    const int bx = blockIdx.x, by = blockIdx.y;
    const int tid = threadIdx.x;
    const int v = tid >> 6, l = tid & 63;
    const int l15 = l & 15, lh = l >> 4;

    const u16* ap = hs + ((size_t)(bx * 128 + v * 32 + l15)) * H_ + lh * 8;
    const u16* bpp = Wo + ((size_t)(by * 64 + l15)) * H_ + lh * 8;

    f32x4 acc0[4] = {f32x4{0,0,0,0}, f32x4{0,0,0,0}, f32x4{0,0,0,0}, f32x4{0,0,0,0}};
    f32x4 acc1[4] = {f32x4{0,0,0,0}, f32x4{0,0,0,0}, f32x4{0,0,0,0}, f32x4{0,0,0,0}};

    #pragma unroll 4
    for (int kk = 0; kk < 32; ++kk) {
        bf16x8 a0 = *(const bf16x8*)(ap + kk * 32);
        bf16x8 a1 = *(const bf16x8*)(ap + (size_t)16 * H_ + kk * 32);
        #pragma unroll
        for (int nt = 0; nt < 4; ++nt) {
            bf16x8 bf = *(const bf16x8*)(bpp + (size_t)nt * 16 * H_ + kk * 32);
            acc0[nt] = __builtin_amdgcn_mfma_f32_16x16x32_bf16(a0, bf, acc0[nt], 0, 0, 0);
            acc1[nt] = __builtin_amdgcn_mfma_f32_16x16x32_bf16(a1, bf, acc1[nt], 0, 0, 0);
        }
    }

    #pragma unroll
    for (int nt = 0; nt < 4; ++nt) {
        const int col = by * 64 + nt * 16 + l15;
        const float bo = b_out[col];
        #pragma unroll
        for (int mt = 0; mt < 2; ++mt) {
            #pragma unroll
            for (int rg = 0; rg < 4; ++rg) {
                const int row = bx * 128 + v * 32 + mt * 16 + lh * 4 + rg;
                const float y = (mt ? acc1[nt][rg] : acc0[nt][rg]) + bo;
                const float sp = (y > 15.f) ? y : log1pf(__expf(y));
                out0[(size_t)row * H_ + col] = y * tanhf(sp);
            }
        }
    }
}

// out1 = broadcast h_f (= hs[:,255,:]), out2 = broadcast c_f (= final c, unscaled)
__global__ __launch_bounds__(256) void bcast2(
    const u16* __restrict__ hs, const float* __restrict__ c_ws,
    float* __restrict__ out1, float* __restrict__ out2)
{
    const size_t total = (size_t)N_ * T_ * H_;
    for (size_t idx = (size_t)blockIdx.x * 256 + threadIdx.x; idx < total;
         idx += (size_t)gridDim.x * 256) {
        const int n = (int)(idx >> 18);
        const int j = (int)(idx & (H_ - 1));
        out1[idx] = bf2f(hs[((size_t)n * T_ + (T_ - 1)) * H_ + j]);
        out2[idx] = c_ws[n * H_ + j];
    }
}

extern "C" void kernel_launch(void* const* d_in, const int* in_sizes, int n_in,
                              void* d_out, int out_size, void* d_ws, size_t ws_size,
                              hipStream_t stream) {
    const float* x      = (const float*)d_in[0];
    const int*   is_ini = (const int*)  d_in[1];
    const float* hx     = (const float*)d_in[2];
    const float* cx     = (const float*)d_in[3];
    const float* W_ih   = (const float*)d_in[4];
    const float* W_hh   = (const float*)d_in[5];
    const float* b_ih   = (const float*)d_in[6];
    const float* b_hh   = (const float*)d_in[7];
    const float* W_out  = (const float*)d_in[8];
    const float* b_out  = (const float*)d_in[9];

    float* out0 = (float*)d_out;
    float* out1 = out0 + (size_t)N_ * T_ * H_;
    float* out2 = out1 + (size_t)N_ * T_ * H_;

    char* ws = (char*)d_ws;
    u16*   x_tb  = (u16*)  (ws + 0);                 // 16,777,216 B
    u16*   Wp    = (u16*)  (ws + 16777216);          // 12,582,912 B
    float* bp    = (float*)(ws + 29360128);          // 16,384 B
    u16*   Wo_b  = (u16*)  (ws + 29376512);          // 2,097,152 B
    u16*   hbuf0 = (u16*)  (ws + 31473664);          // 131,072 B
    u16*   hbuf1 = (u16*)  (ws + 31604736);          // 131,072 B
    float* c_ws  = (float*)(ws + 31735808);          // 262,144 B
    u16*   hs    = (u16*)  (ws + 31997952);          // 33,554,432 B  (end 65,552,384)

    pack_weights<<<4096, 256, 0, stream>>>(W_ih, W_hh, b_ih, b_hh, Wp, bp);
    conv_x<<<dim3(T_, N_), 256, 0, stream>>>(x, x_tb);
    conv_wout<<<1024, 256, 0, stream>>>(W_out, Wo_b);
    init_state2<<<256, 256, 0, stream>>>(hx, cx, is_ini, hbuf0, c_ws);

    for (int t = 0; t < T_; ++t) {
        const u16* hin = (t & 1) ? hbuf1 : hbuf0;
        u16*       hout = (t & 1) ? hbuf0 : hbuf1;
        lstm_step_mfma<<<64, 256, 0, stream>>>(x_tb, Wp, bp, is_ini, hin, hout, c_ws, hs, t);
    }

    out_proj_mfma<<<dim3(128, 16), 256, 0, stream>>>(hs, Wo_b, b_out, out0);
    bcast2<<<2048, 256, 0, stream>>>(hs, c_ws, out1, out2);
}

// Round 4
// 6265.086 us; speedup vs baseline: 16.2326x; 1.3953x over previous
//
#include <hip/hip_runtime.h>
#include <math.h>

#define N_ 64
#define T_ 256
#define I_ 512
#define H_ 1024
#define NWG 64

typedef unsigned short u16;
typedef unsigned int u32;
typedef short bf16x8 __attribute__((ext_vector_type(8)));
typedef float f32x4 __attribute__((ext_vector_type(4)));

__device__ __forceinline__ u16 f2bf(float f) {
    union { float f; unsigned int u; } x; x.f = f;
    unsigned int r = (x.u + 0x7FFFu + ((x.u >> 16) & 1u)) >> 16;
    return (u16)r;
}
__device__ __forceinline__ float bf2f(u16 u) {
    union { unsigned int u; float f; } x; x.u = ((unsigned int)u) << 16;
    return x.f;
}
__device__ __forceinline__ float sigf(float v) {
    return 1.0f / (1.0f + __expf(-v));
}
__device__ __forceinline__ float tanhfast(float x) {
    float e = __expf(2.0f * x);
    return 1.0f - 2.0f / (e + 1.0f);   // NaN-free at +-inf
}

__device__ __forceinline__ void gload_lds16(const void* g, void* l) {
    __builtin_amdgcn_global_load_lds(
        (__attribute__((address_space(1))) void*)(g),
        (__attribute__((address_space(3))) void*)(l), 16, 0, 0);
}

// h fragment-order element index for (n, k): chunk-of-512 elems = (n>>4)*32 + (k>>5),
// within-chunk = (n&15)*32 + ((k>>3)&3)*8 + (k&7). Reads become linear per wave.
__device__ __forceinline__ int hfrag_idx(int n, int k) {
    return (((n >> 4) * 32 + (k >> 5)) << 9) + ((n & 15) << 5) + (((k >> 3) & 3) << 3) + (k & 7);
}

// ---------------- prep kernels ----------------

// Packed row rp = j*4+g : [W_ih[g*H+j][0:512] ; W_hh[g*H+j][0:1024]] bf16
__global__ __launch_bounds__(256) void pack_weights(
    const float* __restrict__ W_ih, const float* __restrict__ W_hh,
    const float* __restrict__ b_ih, const float* __restrict__ b_hh,
    u16* __restrict__ Wp, float* __restrict__ bp)
{
    const int rp = blockIdx.x;            // 0..4095
    const int j = rp >> 2, g = rp & 3;
    const int src = g * H_ + j;
    const float* wi = W_ih + (size_t)src * I_;
    const float* wh = W_hh + (size_t)src * H_;
    u16* dst = Wp + (size_t)rp * (I_ + H_);
    for (int k = threadIdx.x; k < I_; k += 256) dst[k] = f2bf(wi[k]);
    for (int k = threadIdx.x; k < H_; k += 256) dst[I_ + k] = f2bf(wh[k]);
    if (threadIdx.x == 0) bp[rp] = b_ih[src] + b_hh[src];
}

// x (N,T,I) fp32 -> x_tb (T,N,I) bf16
__global__ __launch_bounds__(256) void conv_x(
    const float* __restrict__ x, u16* __restrict__ x_tb)
{
    const int t = blockIdx.x, n = blockIdx.y;
    const float* s = x + ((size_t)n * T_ + t) * I_;
    u16* d = x_tb + ((size_t)t * N_ + n) * I_;
    for (int k = threadIdx.x; k < I_; k += 256) d[k] = f2bf(s[k]);
}

__global__ __launch_bounds__(256) void conv_wout(
    const float* __restrict__ W, u16* __restrict__ Wb)
{
    const size_t base = (size_t)blockIdx.x * 1024 + threadIdx.x;
    #pragma unroll
    for (int q = 0; q < 4; ++q) Wb[base + q * 256] = f2bf(W[base + q * 256]);
}

// rT[t][n] = reset factor (1 - is_init), rT[256][n] = 1
__global__ __launch_bounds__(64) void init_rT(
    const int* __restrict__ is_init, float* __restrict__ rT)
{
    const int t = blockIdx.x;    // 0..256
    const int n = threadIdx.x;   // 0..63
    float r = 1.0f;
    if (t < T_) r = (is_init[n * T_ + t] != 0) ? 0.0f : 1.0f;
    rT[t * 64 + n] = r;
}

// hA = bf16(hx[:,0]*r[0]) in FRAGMENT layout
__global__ __launch_bounds__(256) void init_h0(
    const float* __restrict__ hx, const int* __restrict__ is_init,
    u16* __restrict__ hA)
{
    const int idx = blockIdx.x * 256 + threadIdx.x;   // 65536
    const int n = idx >> 10, j = idx & (H_ - 1);
    const float r = (is_init[n * T_] != 0) ? 0.0f : 1.0f;
    hA[hfrag_idx(n, j)] = f2bf(hx[(size_t)n * T_ * H_ + j] * r);
}

// ---------------- persistent LSTM scan ----------------
// 64 WGs x 256 thr (1 WG/CU). WG w owns units w*16..+15 (packed rows w*64..+63),
// all 64 batches. Wave v: rows w*64+(v>>1)*32 (2 M-frags), batches (v&1)*32 (2 N-frags).
// h-part weights pinned in 256 VGPRs; c state in 4 VGPRs/lane; h exchanged in
// fragment-order global double-buffer; per-WG flag barrier (release/acquire).
__global__ __launch_bounds__(256, 1) void lstm_seq(
    const u16* __restrict__ x_tb,    // [T][64][512]
    const u16* __restrict__ Wp,      // [4096][1536]
    const float* __restrict__ bp,    // [4096]
    const float* __restrict__ rT,    // [257][64]
    const float* __restrict__ cx,    // (N,T,H) fp32
    u16* __restrict__ hA, u16* __restrict__ hB,   // [65536] bf16, fragment order
    float* __restrict__ c_final,     // [64][1024] fp32
    u16* __restrict__ hs,            // [64][256][1024] bf16 (in out2 region)
    u32* __restrict__ flags)         // [64*16], flag[w*16] = steps completed by WG w
{
    __shared__ u16 zls[N_ * H_];     // 128 KB, fragment order (linear copy of hin)
    const int w = blockIdx.x, tid = threadIdx.x;
    const int v = tid >> 6, l = tid & 63;
    const int l15 = l & 15, lh = l >> 4;
    const int mt = v >> 1, ntb = (v & 1) * 32;
    const int rowbase = w * 64 + mt * 32;

    // pin h-part weights in regs: Wh[kk][mi] = rows rowbase+mi*16+l15, k=512+kk*32+lh*8
    bf16x8 Wh[32][2];
    #pragma unroll
    for (int kk = 0; kk < 32; ++kk) {
        #pragma unroll
        for (int mi = 0; mi < 2; ++mi) {
            Wh[kk][mi] = *(const bf16x8*)(
                Wp + (size_t)(rowbase + mi * 16 + l15) * 1536 + I_ + kk * 32 + lh * 8);
        }
    }

    const int jb = (rowbase >> 2) + lh;      // unit (mi=0); mi=1 -> jb+4
    const int n0 = ntb + l15, n1 = n0 + 16;

    float cr0 = cx[(size_t)n0 * T_ * H_ + jb];
    float cr1 = cx[(size_t)n1 * T_ * H_ + jb];
    float cr2 = cx[(size_t)n0 * T_ * H_ + jb + 4];
    float cr3 = cx[(size_t)n1 * T_ * H_ + jb + 4];

    const float4 bias0 = *(const float4*)(bp + 4 * jb);
    const float4 bias1 = *(const float4*)(bp + 4 * (jb + 4));

    // LDS read base (bytes): fragment chunk group (ntb>>4)*32 chunks of 1KB;
    // lane slot l15*64 + lh*16 within chunk; chunk kk at +kk*1024; b1 at +32KB.
    const int zoff = (ntb >> 4) * 32768 + l15 * 64 + lh * 16;

    const u16* axp0 = Wp + (size_t)(rowbase + l15) * 1536 + lh * 8;
    const u16* axp1 = Wp + (size_t)(rowbase + 16 + l15) * 1536 + lh * 8;

    for (int t = 0; t < T_; ++t) {
        const u16* hin = (t & 1) ? hB : hA;
        u16*       hout = (t & 1) ? hA : hB;

        if (t > 0) {
            if (tid < NWG) {
                while (__hip_atomic_load(flags + tid * 16, __ATOMIC_RELAXED,
                                         __HIP_MEMORY_SCOPE_AGENT) < (u32)t)
                    __builtin_amdgcn_s_sleep(1);
            }
            __syncthreads();
            __threadfence();   // acquire: invalidate before reading remote h
        }

        // issue staging: linear copy hin -> LDS (1 KB per wave-instruction)
        {
            const char* hinb = (const char*)hin;
            char* lb = (char*)zls;
            #pragma unroll
            for (int i = 0; i < 32; ++i) {
                const int cb = (v * 32 + i) * 1024;
                gload_lds16(hinb + cb + l * 16, lb + cb);
            }
        }

        f32x4 acc[2][2];
        acc[0][0] = f32x4{0.f, 0.f, 0.f, 0.f};
        acc[0][1] = f32x4{0.f, 0.f, 0.f, 0.f};
        acc[1][0] = f32x4{0.f, 0.f, 0.f, 0.f};
        acc[1][1] = f32x4{0.f, 0.f, 0.f, 0.f};

        // x part: K=512 (independent of LDS -> overlaps staging latency)
        const u16* bxp0 = x_tb + ((size_t)t * N_ + n0) * I_ + lh * 8;
        const u16* bxp1 = x_tb + ((size_t)t * N_ + n1) * I_ + lh * 8;
        #pragma unroll
        for (int kk = 0; kk < 16; ++kk) {
            bf16x8 a0 = *(const bf16x8*)(axp0 + kk * 32);
            bf16x8 a1 = *(const bf16x8*)(axp1 + kk * 32);
            bf16x8 b0 = *(const bf16x8*)(bxp0 + kk * 32);
            bf16x8 b1 = *(const bf16x8*)(bxp1 + kk * 32);
            acc[0][0] = __builtin_amdgcn_mfma_f32_16x16x32_bf16(a0, b0, acc[0][0], 0, 0, 0);
            acc[0][1] = __builtin_amdgcn_mfma_f32_16x16x32_bf16(a0, b1, acc[0][1], 0, 0, 0);
            acc[1][0] = __builtin_amdgcn_mfma_f32_16x16x32_bf16(a1, b0, acc[1][0], 0, 0, 0);
            acc[1][1] = __builtin_amdgcn_mfma_f32_16x16x32_bf16(a1, b1, acc[1][1], 0, 0, 0);
        }

        asm volatile("s_waitcnt vmcnt(0)" ::: "memory");
        __syncthreads();

        // h part: K=1024, A from regs, B from LDS (conflict-free linear reads)
        const char* zp = (const char*)zls;
        #pragma unroll
        for (int kk = 0; kk < 32; ++kk) {
            bf16x8 b0 = *(const bf16x8*)(zp + zoff + kk * 1024);
            bf16x8 b1 = *(const bf16x8*)(zp + zoff + 32768 + kk * 1024);
            acc[0][0] = __builtin_amdgcn_mfma_f32_16x16x32_bf16(Wh[kk][0], b0, acc[0][0], 0, 0, 0);
            acc[0][1] = __builtin_amdgcn_mfma_f32_16x16x32_bf16(Wh[kk][0], b1, acc[0][1], 0, 0, 0);
            acc[1][0] = __builtin_amdgcn_mfma_f32_16x16x32_bf16(Wh[kk][1], b0, acc[1][0], 0, 0, 0);
            acc[1][1] = __builtin_amdgcn_mfma_f32_16x16x32_bf16(Wh[kk][1], b1, acc[1][1], 0, 0, 0);
        }

        // epilogue: 4 (n,j) cells per lane; gates i,f,g,o in acc[mi][ni][0..3]
        const float rt0 = rT[t * 64 + n0],       rt1 = rT[t * 64 + n1];
        const float rn0 = rT[(t + 1) * 64 + n0], rn1 = rT[(t + 1) * 64 + n1];

#define CELL(mi, ni, CR) {                                                  \
        const int n = (ni) ? n1 : n0;                                       \
        const int j = jb + (mi) * 4;                                        \
        const float4 bi = (mi) ? bias1 : bias0;                             \
        const float rt = (ni) ? rt1 : rt0;                                  \
        const float rn = (ni) ? rn1 : rn0;                                  \
        const float ig = acc[mi][ni][0] + bi.x;                             \
        const float fg = acc[mi][ni][1] + bi.y;                             \
        const float gg = acc[mi][ni][2] + bi.z;                             \
        const float og = acc[mi][ni][3] + bi.w;                             \
        const float cc = CR * rt;                                           \
        const float cn = sigf(fg) * cc + sigf(ig) * tanhfast(gg);           \
        const float hv = sigf(og) * tanhfast(cn);                           \
        CR = cn;                                                            \
        hs[((size_t)n * T_ + t) * H_ + j] = f2bf(hv);                       \
        hout[hfrag_idx(n, j)] = f2bf(hv * rn);                              \
        if (t == T_ - 1) c_final[n * H_ + j] = cn;                          \
    }
        CELL(0, 0, cr0) CELL(0, 1, cr1) CELL(1, 0, cr2) CELL(1, 1, cr3)
#undef CELL

        __threadfence();   // release: push h/hs stores to agent scope
        __syncthreads();
        if (tid == 0)
            __hip_atomic_store(flags + w * 16, (u32)(t + 1), __ATOMIC_RELEASE,
                               __HIP_MEMORY_SCOPE_AGENT);
    }
}

// ---------------- output projection (MFMA GEMM + mish) ----------------
__global__ __launch_bounds__(256) void out_proj_mfma(
    const u16* __restrict__ hs, const u16* __restrict__ Wo,
    const float* __restrict__ b_out, float* __restrict__ out0)
{
    const int bx = blockIdx.x, by = blockIdx.y;
    const int tid = threadIdx.x;
    const int v = tid >> 6, l = tid & 63;
    const int l15 = l & 15, lh = l >> 4;

    const u16* ap = hs + ((size_t)(bx * 128 + v * 32 + l15)) * H_ + lh * 8;
    const u16* bpp = Wo + ((size_t)(by * 64 + l15)) * H_ + lh * 8;

    f32x4 acc0[4] = {f32x4{0,0,0,0}, f32x4{0,0,0,0}, f32x4{0,0,0,0}, f32x4{0,0,0,0}};
    f32x4 acc1[4] = {f32x4{0,0,0,0}, f32x4{0,0,0,0}, f32x4{0,0,0,0}, f32x4{0,0,0,0}};

    #pragma unroll 4
    for (int kk = 0; kk < 32; ++kk) {
        bf16x8 a0 = *(const bf16x8*)(ap + kk * 32);
        bf16x8 a1 = *(const bf16x8*)(ap + (size_t)16 * H_ + kk * 32);
        #pragma unroll
        for (int nt = 0; nt < 4; ++nt) {
            bf16x8 bf = *(const bf16x8*)(bpp + (size_t)nt * 16 * H_ + kk * 32);
            acc0[nt] = __builtin_amdgcn_mfma_f32_16x16x32_bf16(a0, bf, acc0[nt], 0, 0, 0);
            acc1[nt] = __builtin_amdgcn_mfma_f32_16x16x32_bf16(a1, bf, acc1[nt], 0, 0, 0);
        }
    }

    #pragma unroll
    for (int nt = 0; nt < 4; ++nt) {
        const int col = by * 64 + nt * 16 + l15;
        const float bo = b_out[col];
        #pragma unroll
        for (int mt = 0; mt < 2; ++mt) {
            #pragma unroll
            for (int rg = 0; rg < 4; ++rg) {
                const int row = bx * 128 + v * 32 + mt * 16 + lh * 4 + rg;
                const float y = (mt ? acc1[nt][rg] : acc0[nt][rg]) + bo;
                const float sp = (y > 15.f) ? y : log1pf(__expf(y));
                out0[(size_t)row * H_ + col] = y * tanhfast(sp);
            }
        }
    }
}

// out1 = broadcast hs[:,255,:]  (hs lives in out2 region, read before overwrite)
__global__ __launch_bounds__(256) void bcast_h(
    const u16* __restrict__ hs, float* __restrict__ out1)
{
    const size_t total = (size_t)N_ * T_ * H_;
    for (size_t idx = (size_t)blockIdx.x * 256 + threadIdx.x; idx < total;
         idx += (size_t)gridDim.x * 256) {
        const int n = (int)(idx >> 18);
        const int j = (int)(idx & (H_ - 1));
        out1[idx] = bf2f(hs[((size_t)n * T_ + (T_ - 1)) * H_ + j]);
    }
}

// out2 = broadcast c_final  (runs LAST; overwrites the hs scratch region)
__global__ __launch_bounds__(256) void bcast_c(
    const float* __restrict__ c_final, float* __restrict__ out2)
{
    const size_t total = (size_t)N_ * T_ * H_;
    for (size_t idx = (size_t)blockIdx.x * 256 + threadIdx.x; idx < total;
         idx += (size_t)gridDim.x * 256) {
        const int n = (int)(idx >> 18);
        const int j = (int)(idx & (H_ - 1));
        out2[idx] = c_final[n * H_ + j];
    }
}

extern "C" void kernel_launch(void* const* d_in, const int* in_sizes, int n_in,
                              void* d_out, int out_size, void* d_ws, size_t ws_size,
                              hipStream_t stream) {
    const float* x      = (const float*)d_in[0];
    const int*   is_ini = (const int*)  d_in[1];
    const float* hx     = (const float*)d_in[2];
    const float* cx     = (const float*)d_in[3];
    const float* W_ih   = (const float*)d_in[4];
    const float* W_hh   = (const float*)d_in[5];
    const float* b_ih   = (const float*)d_in[6];
    const float* b_hh   = (const float*)d_in[7];
    const float* W_out  = (const float*)d_in[8];
    const float* b_out  = (const float*)d_in[9];

    float* out0 = (float*)d_out;
    float* out1 = out0 + (size_t)N_ * T_ * H_;
    float* out2 = out1 + (size_t)N_ * T_ * H_;

    char* ws = (char*)d_ws;
    u16*   x_tb    = (u16*)  (ws + 0);          // 16,777,216
    u16*   Wp      = (u16*)  (ws + 16777216);   // 12,582,912
    float* bp      = (float*)(ws + 29360128);   // 16,384
    u16*   Wo_b    = (u16*)  (ws + 29376512);   // 2,097,152
    u16*   hA      = (u16*)  (ws + 31473664);   // 131,072
    u16*   hB      = (u16*)  (ws + 31604736);   // 131,072
    float* c_final = (float*)(ws + 31735808);   // 262,144
    float* rT      = (float*)(ws + 31997952);   // 65,792
    u32*   flags   = (u32*)  (ws + 32063744);   // 4,096   (end ~32.07 MB)

    u16* hs = (u16*)out2;   // 33.5 MB scratch inside out2 region

    hipMemsetAsync(flags, 0, NWG * 16 * sizeof(u32), stream);
    pack_weights<<<4096, 256, 0, stream>>>(W_ih, W_hh, b_ih, b_hh, Wp, bp);
    conv_x<<<dim3(T_, N_), 256, 0, stream>>>(x, x_tb);
    conv_wout<<<1024, 256, 0, stream>>>(W_out, Wo_b);
    init_rT<<<T_ + 1, 64, 0, stream>>>(is_ini, rT);
    init_h0<<<256, 256, 0, stream>>>(hx, is_ini, hA);

    lstm_seq<<<NWG, 256, 0, stream>>>(x_tb, Wp, bp, rT, cx, hA, hB, c_final, hs, flags);

    out_proj_mfma<<<dim3(128, 16), 256, 0, stream>>>(hs, Wo_b, b_out, out0);
    bcast_h<<<2048, 256, 0, stream>>>(hs, out1);
    bcast_c<<<2048, 256, 0, stream>>>(c_final, out2);
}

// Round 7
// 3246.621 us; speedup vs baseline: 31.3245x; 1.9297x over previous
//
#include <hip/hip_runtime.h>
#include <math.h>

#define N_ 64
#define T_ 256
#define I_ 512
#define H_ 1024
#define NWG 64

typedef unsigned short u16;
typedef unsigned int u32;
typedef short bf16x8 __attribute__((ext_vector_type(8)));
typedef float f32x4 __attribute__((ext_vector_type(4)));

__device__ __forceinline__ u16 f2bf(float f) {
    union { float f; unsigned int u; } x; x.f = f;
    unsigned int r = (x.u + 0x7FFFu + ((x.u >> 16) & 1u)) >> 16;
    return (u16)r;
}
__device__ __forceinline__ float bf2f(u16 u) {
    union { unsigned int u; float f; } x; x.u = ((unsigned int)u) << 16;
    return x.f;
}
__device__ __forceinline__ float sigf(float v) {
    return 1.0f / (1.0f + __expf(-v));
}
__device__ __forceinline__ float tanhfast(float x) {
    float e = __expf(2.0f * x);
    return 1.0f - 2.0f / (e + 1.0f);   // NaN-free at +-inf
}

// aux=17 = SC0|SC1 cache policy: bypass L1/L2, read at IC (agent-coherent point)
__device__ __forceinline__ void gload_lds16_bypass(const void* g, void* l) {
    __builtin_amdgcn_global_load_lds(
        (__attribute__((address_space(1))) void*)(g),
        (__attribute__((address_space(3))) void*)(l), 16, 0, 17);
}

// h fragment-order element index for (n, k): chunk-of-512 elems = (n>>4)*32 + (k>>5),
// within-chunk = (n&15)*32 + ((k>>3)&3)*8 + (k&7). Staging is a linear copy.
__device__ __forceinline__ int hfrag_idx(int n, int k) {
    return (((n >> 4) * 32 + (k >> 5)) << 9) + ((n & 15) << 5) + (((k >> 3) & 3) << 3) + (k & 7);
}

// ---------------- prep kernels ----------------

// Packed row rp = j*4+g : [W_ih[g*H+j][0:512] ; W_hh[g*H+j][0:1024]] bf16
__global__ __launch_bounds__(256) void pack_weights(
    const float* __restrict__ W_ih, const float* __restrict__ W_hh,
    const float* __restrict__ b_ih, const float* __restrict__ b_hh,
    u16* __restrict__ Wp, float* __restrict__ bp)
{
    const int rp = blockIdx.x;            // 0..4095
    const int j = rp >> 2, g = rp & 3;
    const int src = g * H_ + j;
    const float* wi = W_ih + (size_t)src * I_;
    const float* wh = W_hh + (size_t)src * H_;
    u16* dst = Wp + (size_t)rp * (I_ + H_);
    for (int k = threadIdx.x; k < I_; k += 256) dst[k] = f2bf(wi[k]);
    for (int k = threadIdx.x; k < H_; k += 256) dst[I_ + k] = f2bf(wh[k]);
    if (threadIdx.x == 0) bp[rp] = b_ih[src] + b_hh[src];
}

__global__ __launch_bounds__(256) void conv_x(
    const float* __restrict__ x, u16* __restrict__ x_tb)
{
    const int t = blockIdx.x, n = blockIdx.y;
    const float* s = x + ((size_t)n * T_ + t) * I_;
    u16* d = x_tb + ((size_t)t * N_ + n) * I_;
    for (int k = threadIdx.x; k < I_; k += 256) d[k] = f2bf(s[k]);
}

__global__ __launch_bounds__(256) void conv_wout(
    const float* __restrict__ W, u16* __restrict__ Wb)
{
    const size_t base = (size_t)blockIdx.x * 1024 + threadIdx.x;
    #pragma unroll
    for (int q = 0; q < 4; ++q) Wb[base + q * 256] = f2bf(W[base + q * 256]);
}

__global__ __launch_bounds__(64) void init_rT(
    const int* __restrict__ is_init, float* __restrict__ rT)
{
    const int t = blockIdx.x;    // 0..256
    const int n = threadIdx.x;   // 0..63
    float r = 1.0f;
    if (t < T_) r = (is_init[n * T_ + t] != 0) ? 0.0f : 1.0f;
    rT[t * 64 + n] = r;
}

// hA = bf16(hx[:,0]*r[0]) in FRAGMENT layout
__global__ __launch_bounds__(256) void init_h0(
    const float* __restrict__ hx, const int* __restrict__ is_init,
    u16* __restrict__ hA)
{
    const int idx = blockIdx.x * 256 + threadIdx.x;   // 65536
    const int n = idx >> 10, j = idx & (H_ - 1);
    const float r = (is_init[n * T_] != 0) ? 0.0f : 1.0f;
    hA[hfrag_idx(n, j)] = f2bf(hx[(size_t)n * T_ * H_ + j] * r);
}

// ---------------- persistent LSTM scan ----------------
// 64 WGs x 256 thr (1 WG/CU). WG w owns units w*16..+15 (packed rows w*64..+63),
// all 64 batches. Wave v: rows w*64+(v>>1)*32 (2 M-frags), batches (v&1)*32.
// NO fences: h written via agent-scope write-through u32 atomics (pairs packed
// via shfl), h read via global_load_lds aux=SC0|SC1 (IC bypass). L2 stays warm.
__global__ __launch_bounds__(256, 1) void lstm_seq(
    const u16* __restrict__ x_tb,    // [T][64][512]
    const u16* __restrict__ Wp,      // [4096][1536]
    const float* __restrict__ bp,    // [4096]
    const float* __restrict__ rT,    // [257][64]
    const float* __restrict__ cx,    // (N,T,H) fp32
    u16* __restrict__ hA, u16* __restrict__ hB,   // [65536] bf16, fragment order
    float* __restrict__ c_final,     // [64][1024] fp32
    u16* __restrict__ hs,            // [64][256][1024] bf16 (in out2 region)
    u32* __restrict__ flags)         // [64*16], flag[w*16] = steps completed by WG w
{
    __shared__ u16 zls[N_ * H_];     // 128 KB, fragment order (linear copy of hin)
    const int w = blockIdx.x, tid = threadIdx.x;
    const int v = tid >> 6, l = tid & 63;
    const int l15 = l & 15, lh = l >> 4;
    const int mt = v >> 1, ntb = (v & 1) * 32;
    const int rowbase = w * 64 + mt * 32;

    // h-part weights: Wh[kk][mi] = row (rowbase + mi*16 + l15), k = 512 + kk*32 + lh*8
    bf16x8 Wh[32][2];
    #pragma unroll
    for (int kk = 0; kk < 32; ++kk) {
        #pragma unroll
        for (int mi = 0; mi < 2; ++mi) {
            Wh[kk][mi] = *(const bf16x8*)(
                Wp + (size_t)(rowbase + mi * 16 + l15) * 1536 + I_ + kk * 32 + lh * 8);
        }
    }

    const int jb = (rowbase >> 2) + lh;      // unit (mi=0); mi=1 -> jb+4
    const int n0 = ntb + l15, n1 = n0 + 16;

    float cr0 = cx[(size_t)n0 * T_ * H_ + jb];
    float cr1 = cx[(size_t)n1 * T_ * H_ + jb];
    float cr2 = cx[(size_t)n0 * T_ * H_ + jb + 4];
    float cr3 = cx[(size_t)n1 * T_ * H_ + jb + 4];

    const float4 bias0 = *(const float4*)(bp + 4 * jb);
    const float4 bias1 = *(const float4*)(bp + 4 * (jb + 4));

    // LDS read base (bytes): group (ntb>>4)*32 chunks of 1KB; lane slot l15*64+lh*16.
    const int zoff = (ntb >> 4) * 32768 + l15 * 64 + lh * 16;

    const u16* axp0 = Wp + (size_t)(rowbase + l15) * 1536 + lh * 8;
    const u16* axp1 = Wp + (size_t)(rowbase + 16 + l15) * 1536 + lh * 8;

    for (int t = 0; t < T_; ++t) {
        const u16* hin = (t & 1) ? hB : hA;
        u16*       hout = (t & 1) ? hA : hB;

        if (t > 0) {
            if (tid < NWG) {
                while (__hip_atomic_load(flags + tid * 16, __ATOMIC_RELAXED,
                                         __HIP_MEMORY_SCOPE_AGENT) < (u32)t)
                    __builtin_amdgcn_s_sleep(1);
            }
            __syncthreads();
        }

        // stage hin -> LDS (linear copy, IC-bypass reads; dest = base + lane*16)
        {
            const char* hinb = (const char*)hin;
            char* lb = (char*)zls;
            #pragma unroll
            for (int i = 0; i < 32; ++i) {
                const int cb = (v * 32 + i) * 1024;
                gload_lds16_bypass(hinb + cb + l * 16, lb + cb);
            }
        }

        f32x4 acc00 = {0.f, 0.f, 0.f, 0.f}, acc01 = {0.f, 0.f, 0.f, 0.f};
        f32x4 acc10 = {0.f, 0.f, 0.f, 0.f}, acc11 = {0.f, 0.f, 0.f, 0.f};

        // ---- x part: K=512, cached loads (L2 warm — never invalidated) ----
        const u16* bxp0 = x_tb + ((size_t)t * N_ + n0) * I_ + lh * 8;
        const u16* bxp1 = x_tb + ((size_t)t * N_ + n1) * I_ + lh * 8;
        #pragma unroll
        for (int kk = 0; kk < 16; ++kk) {
            bf16x8 a0 = *(const bf16x8*)(axp0 + kk * 32);
            bf16x8 a1 = *(const bf16x8*)(axp1 + kk * 32);
            bf16x8 b0 = *(const bf16x8*)(bxp0 + kk * 32);
            bf16x8 b1 = *(const bf16x8*)(bxp1 + kk * 32);
            acc00 = __builtin_amdgcn_mfma_f32_16x16x32_bf16(a0, b0, acc00, 0, 0, 0);
            acc01 = __builtin_amdgcn_mfma_f32_16x16x32_bf16(a0, b1, acc01, 0, 0, 0);
            acc10 = __builtin_amdgcn_mfma_f32_16x16x32_bf16(a1, b0, acc10, 0, 0, 0);
            acc11 = __builtin_amdgcn_mfma_f32_16x16x32_bf16(a1, b1, acc11, 0, 0, 0);
        }

        asm volatile("s_waitcnt vmcnt(0)" ::: "memory");
        __syncthreads();

        // ---- h part: K=1024, A from regs, B from LDS (conflict-free linear) ----
        const char* zp = (const char*)zls;
        #pragma unroll
        for (int kk = 0; kk < 32; ++kk) {
            bf16x8 b0 = *(const bf16x8*)(zp + zoff + kk * 1024);
            bf16x8 b1 = *(const bf16x8*)(zp + zoff + 32768 + kk * 1024);
            acc00 = __builtin_amdgcn_mfma_f32_16x16x32_bf16(Wh[kk][0], b0, acc00, 0, 0, 0);
            acc01 = __builtin_amdgcn_mfma_f32_16x16x32_bf16(Wh[kk][0], b1, acc01, 0, 0, 0);
            acc10 = __builtin_amdgcn_mfma_f32_16x16x32_bf16(Wh[kk][1], b0, acc10, 0, 0, 0);
            acc11 = __builtin_amdgcn_mfma_f32_16x16x32_bf16(Wh[kk][1], b1, acc11, 0, 0, 0);
        }

        // ---- epilogue: 4 cells/lane; gates i,f,g,o in acc[mi][ni][0..3] ----
        const float rt0 = rT[t * 64 + n0],        rt1 = rT[t * 64 + n1];
        const float rn0 = rT[(t + 1) * 64 + n0],  rn1 = rT[(t + 1) * 64 + n1];

        float hv00, hv01, hv10, hv11;
#define CELL(ACC, BI, CC, RT, HV) { \
        const float ig = ACC[0] + BI.x; \
        const float fg = ACC[1] + BI.y; \
        const float gg = ACC[2] + BI.z; \
        const float og = ACC[3] + BI.w; \
        const float cn = sigf(fg) * (CC * RT) + sigf(ig) * tanhfast(gg); \
        HV = sigf(og) * tanhfast(cn); \
        CC = cn; }
        CELL(acc00, bias0, cr0, rt0, hv00)
        CELL(acc01, bias0, cr1, rt1, hv01)
        CELL(acc10, bias1, cr2, rt0, hv10)
        CELL(acc11, bias1, cr3, rt1, hv11)
#undef CELL

        // ---- h exchange: pair (jb, jb+1 via lane+16), u32 agent write-through ----
        const float s00 = hv00 * rn0, s01 = hv01 * rn1;
        const float s10 = hv10 * rn0, s11 = hv11 * rn1;
        const float p00 = __shfl_down(s00, 16), p01 = __shfl_down(s01, 16);
        const float p10 = __shfl_down(s10, 16), p11 = __shfl_down(s11, 16);
        if (!(lh & 1)) {
            const u32 v00 = (u32)f2bf(s00) | ((u32)f2bf(p00) << 16);
            const u32 v01 = (u32)f2bf(s01) | ((u32)f2bf(p01) << 16);
            const u32 v10 = (u32)f2bf(s10) | ((u32)f2bf(p10) << 16);
            const u32 v11 = (u32)f2bf(s11) | ((u32)f2bf(p11) << 16);
            __hip_atomic_store((u32*)(hout + hfrag_idx(n0, jb)), v00,
                               __ATOMIC_RELAXED, __HIP_MEMORY_SCOPE_AGENT);
            __hip_atomic_store((u32*)(hout + hfrag_idx(n1, jb)), v01,
                               __ATOMIC_RELAXED, __HIP_MEMORY_SCOPE_AGENT);
            __hip_atomic_store((u32*)(hout + hfrag_idx(n0, jb + 4)), v10,
                               __ATOMIC_RELAXED, __HIP_MEMORY_SCOPE_AGENT);
            __hip_atomic_store((u32*)(hout + hfrag_idx(n1, jb + 4)), v11,
                               __ATOMIC_RELAXED, __HIP_MEMORY_SCOPE_AGENT);
        }
        asm volatile("s_waitcnt vmcnt(0)" ::: "memory");   // release: h acked at IC
        __syncthreads();
        if (tid == 0)
            __hip_atomic_store(flags + w * 16, (u32)(t + 1),
                               __ATOMIC_RELAXED, __HIP_MEMORY_SCOPE_AGENT);

        // hs (plain cached, off critical path — next dispatch reads it)
        hs[((size_t)n0 * T_ + t) * H_ + jb]     = f2bf(hv00);
        hs[((size_t)n1 * T_ + t) * H_ + jb]     = f2bf(hv01);
        hs[((size_t)n0 * T_ + t) * H_ + jb + 4] = f2bf(hv10);
        hs[((size_t)n1 * T_ + t) * H_ + jb + 4] = f2bf(hv11);

        if (t == T_ - 1) {
            c_final[(size_t)n0 * H_ + jb]     = cr0;
            c_final[(size_t)n1 * H_ + jb]     = cr1;
            c_final[(size_t)n0 * H_ + jb + 4] = cr2;
            c_final[(size_t)n1 * H_ + jb + 4] = cr3;
        }
    }
}

// ---------------- output projection (MFMA GEMM + mish) ----------------
__global__ __launch_bounds__(256) void out_proj_mfma(
    const u16* __restrict__ hs, const u16* __restrict__ Wo,
    const float* __restrict__ b_out, float* __restrict__ out0)
{
    const int bx = blockIdx.x, by = blockIdx.y;
    const int tid = threadIdx.x;
    const int v = tid >> 6, l = tid & 63;
    const int l15 = l & 15, lh = l >> 4;

    const u16* ap = hs + ((size_t)(bx * 128 + v * 32 + l15)) * H_ + lh * 8;
    const u16* bpp = Wo + ((size_t)(by * 64 + l15)) * H_ + lh * 8;

    f32x4 acc0[4] = {f32x4{0,0,0,0}, f32x4{0,0,0,0}, f32x4{0,0,0,0}, f32x4{0,0,0,0}};
    f32x4 acc1[4] = {f32x4{0,0,0,0}, f32x4{0,0,0,0}, f32x4{0,0,0,0}, f32x4{0,0,0,0}};

    #pragma unroll 4
    for (int kk = 0; kk < 32; ++kk) {
        bf16x8 a0 = *(const bf16x8*)(ap + kk * 32);
        bf16x8 a1 = *(const bf16x8*)(ap + (size_t)16 * H_ + kk * 32);
        #pragma unroll
        for (int nt = 0; nt < 4; ++nt) {
            bf16x8 bf = *(const bf16x8*)(bpp + (size_t)nt * 16 * H_ + kk * 32);
            acc0[nt] = __builtin_amdgcn_mfma_f32_16x16x32_bf16(a0, bf, acc0[nt], 0, 0, 0);
            acc1[nt] = __builtin_amdgcn_mfma_f32_16x16x32_bf16(a1, bf, acc1[nt], 0, 0, 0);
        }
    }

    #pragma unroll
    for (int nt = 0; nt < 4; ++nt) {
        const int col = by * 64 + nt * 16 + l15;
        const float bo = b_out[col];
        #pragma unroll
        for (int mtq = 0; mtq < 2; ++mtq) {
            #pragma unroll
            for (int rg = 0; rg < 4; ++rg) {
                const int row = bx * 128 + v * 32 + mtq * 16 + lh * 4 + rg;
                const float y = (mtq ? acc1[nt][rg] : acc0[nt][rg]) + bo;
                const float sp = (y > 15.f) ? y : log1pf(__expf(y));
                out0[(size_t)row * H_ + col] = y * tanhfast(sp);
            }
        }
    }
}

__global__ __launch_bounds__(256) void bcast_h(
    const u16* __restrict__ hs, float* __restrict__ out1)
{
    const size_t total = (size_t)N_ * T_ * H_;
    for (size_t idx = (size_t)blockIdx.x * 256 + threadIdx.x; idx < total;
         idx += (size_t)gridDim.x * 256) {
        const int n = (int)(idx >> 18);
        const int j = (int)(idx & (H_ - 1));
        out1[idx] = bf2f(hs[((size_t)n * T_ + (T_ - 1)) * H_ + j]);
    }
}

__global__ __launch_bounds__(256) void bcast_c(
    const float* __restrict__ c_final, float* __restrict__ out2)
{
    const size_t total = (size_t)N_ * T_ * H_;
    for (size_t idx = (size_t)blockIdx.x * 256 + threadIdx.x; idx < total;
         idx += (size_t)gridDim.x * 256) {
        const int n = (int)(idx >> 18);
        const int j = (int)(idx & (H_ - 1));
        out2[idx] = c_final[n * H_ + j];
    }
}

extern "C" void kernel_launch(void* const* d_in, const int* in_sizes, int n_in,
                              void* d_out, int out_size, void* d_ws, size_t ws_size,
                              hipStream_t stream) {
    const float* x      = (const float*)d_in[0];
    const int*   is_ini = (const int*)  d_in[1];
    const float* hx     = (const float*)d_in[2];
    const float* cx     = (const float*)d_in[3];
    const float* W_ih   = (const float*)d_in[4];
    const float* W_hh   = (const float*)d_in[5];
    const float* b_ih   = (const float*)d_in[6];
    const float* b_hh   = (const float*)d_in[7];
    const float* W_out  = (const float*)d_in[8];
    const float* b_out  = (const float*)d_in[9];

    float* out0 = (float*)d_out;
    float* out1 = out0 + (size_t)N_ * T_ * H_;
    float* out2 = out1 + (size_t)N_ * T_ * H_;

    char* ws = (char*)d_ws;
    u16*   x_tb    = (u16*)  (ws + 0);          // 16,777,216
    u16*   Wp      = (u16*)  (ws + 16777216);   // 12,582,912
    float* bp      = (float*)(ws + 29360128);   // 16,384
    u16*   Wo_b    = (u16*)  (ws + 29376512);   // 2,097,152
    u16*   hA      = (u16*)  (ws + 31473664);   // 131,072
    u16*   hB      = (u16*)  (ws + 31604736);   // 131,072
    float* c_final = (float*)(ws + 31735808);   // 262,144
    float* rT      = (float*)(ws + 31997952);   // 65,792
    u32*   flags   = (u32*)  (ws + 32063744);   // 4,096

    u16* hs = (u16*)out2;   // 33.5 MB scratch inside out2 region

    hipMemsetAsync(flags, 0, NWG * 16 * sizeof(u32), stream);
    pack_weights<<<4096, 256, 0, stream>>>(W_ih, W_hh, b_ih, b_hh, Wp, bp);
    conv_x<<<dim3(T_, N_), 256, 0, stream>>>(x, x_tb);
    conv_wout<<<1024, 256, 0, stream>>>(W_out, Wo_b);
    init_rT<<<T_ + 1, 64, 0, stream>>>(is_ini, rT);
    init_h0<<<256, 256, 0, stream>>>(hx, is_ini, hA);

    lstm_seq<<<NWG, 256, 0, stream>>>(x_tb, Wp, bp, rT, cx, hA, hB, c_final, hs, flags);

    out_proj_mfma<<<dim3(128, 16), 256, 0, stream>>>(hs, Wo_b, b_out, out0);
    bcast_h<<<2048, 256, 0, stream>>>(hs, out1);
    bcast_c<<<2048, 256, 0, stream>>>(c_final, out2);
}

// Round 9
// 2092.632 us; speedup vs baseline: 48.5986x; 1.5515x over previous
//
#include <hip/hip_runtime.h>
#include <math.h>

#define N_ 64
#define T_ 256
#define I_ 512
#define H_ 1024
#define NWG 64

typedef unsigned short u16;
typedef unsigned int u32;
typedef short bf16x8 __attribute__((ext_vector_type(8)));
typedef float f32x4 __attribute__((ext_vector_type(4)));
typedef u16 u16x4 __attribute__((ext_vector_type(4)));

__device__ __forceinline__ u16 f2bf(float f) {
    union { float f; unsigned int u; } x; x.f = f;
    unsigned int r = (x.u + 0x7FFFu + ((x.u >> 16) & 1u)) >> 16;
    return (u16)r;
}
__device__ __forceinline__ float bf2f(u16 u) {
    union { unsigned int u; float f; } x; x.u = ((unsigned int)u) << 16;
    return x.f;
}
__device__ __forceinline__ float sigf(float v) {
    return 1.0f / (1.0f + __expf(-v));
}
__device__ __forceinline__ float tanhfast(float x) {
    float e = __expf(2.0f * x);
    return 1.0f - 2.0f / (e + 1.0f);   // NaN-free at +-inf
}

// aux=17 = SC0|SC1: bypass L1/L2, read at IC (device coherence point) [proven r7]
__device__ __forceinline__ void gload_lds16_bypass(const void* g, void* l) {
    __builtin_amdgcn_global_load_lds(
        (__attribute__((address_space(1))) void*)(g),
        (__attribute__((address_space(3))) void*)(l), 16, 0, 17);
}

#define VMW(Ncnt) do { \
    asm volatile("s_waitcnt vmcnt(" #Ncnt ")" ::: "memory"); \
    __builtin_amdgcn_sched_barrier(0); } while (0)

// h fragment-order element index for (n, k): chunk-of-512 elems = (n>>4)*32 + (k>>5),
// within-chunk = (n&15)*32 + ((k>>3)&3)*8 + (k&7). Staging is a linear copy.
__device__ __forceinline__ int hfrag_idx(int n, int k) {
    return (((n >> 4) * 32 + (k >> 5)) << 9) + ((n & 15) << 5) + (((k >> 3) & 3) << 3) + (k & 7);
}

// ---------------- prep kernels ----------------

// Packed row rp = j*4+g : [W_ih[g*H+j][0:512] ; W_hh[g*H+j][0:1024]] bf16
__global__ __launch_bounds__(256) void pack_weights(
    const float* __restrict__ W_ih, const float* __restrict__ W_hh,
    const float* __restrict__ b_ih, const float* __restrict__ b_hh,
    u16* __restrict__ Wp, float* __restrict__ bp)
{
    const int rp = blockIdx.x;            // 0..4095
    const int j = rp >> 2, g = rp & 3;
    const int src = g * H_ + j;
    const float* wi = W_ih + (size_t)src * I_;
    const float* wh = W_hh + (size_t)src * H_;
    u16* dst = Wp + (size_t)rp * (I_ + H_);
    for (int k = threadIdx.x; k < I_; k += 256) dst[k] = f2bf(wi[k]);
    for (int k = threadIdx.x; k < H_; k += 256) dst[I_ + k] = f2bf(wh[k]);
    if (threadIdx.x == 0) bp[rp] = b_ih[src] + b_hh[src];
}

__global__ __launch_bounds__(256) void conv_x(
    const float* __restrict__ x, u16* __restrict__ x_tb)
{
    const int t = blockIdx.x, n = blockIdx.y;
    const float* s = x + ((size_t)n * T_ + t) * I_;
    u16* d = x_tb + ((size_t)t * N_ + n) * I_;
    for (int k = threadIdx.x; k < I_; k += 256) d[k] = f2bf(s[k]);
}

__global__ __launch_bounds__(256) void conv_wout(
    const float* __restrict__ W, u16* __restrict__ Wb)
{
    const size_t base = (size_t)blockIdx.x * 1024 + threadIdx.x;
    #pragma unroll
    for (int q = 0; q < 4; ++q) Wb[base + q * 256] = f2bf(W[base + q * 256]);
}

__global__ __launch_bounds__(64) void init_rT(
    const int* __restrict__ is_init, float* __restrict__ rT)
{
    const int t = blockIdx.x;    // 0..256
    const int n = threadIdx.x;   // 0..63
    float r = 1.0f;
    if (t < T_) r = (is_init[n * T_ + t] != 0) ? 0.0f : 1.0f;
    rT[t * 64 + n] = r;
}

// hA = bf16(hx[:,0]*r[0]) in FRAGMENT layout
__global__ __launch_bounds__(256) void init_h0(
    const float* __restrict__ hx, const int* __restrict__ is_init,
    u16* __restrict__ hA)
{
    const int idx = blockIdx.x * 256 + threadIdx.x;   // 65536
    const int n = idx >> 10, j = idx & (H_ - 1);
    const float r = (is_init[n * T_] != 0) ? 0.0f : 1.0f;
    hA[hfrag_idx(n, j)] = f2bf(hx[(size_t)n * T_ * H_ + j] * r);
}

// ---------------- x-gate precompute (parallel MFMA GEMM) ----------------
// Xg[row=(t*64+n)][p] = bf16( x_tb[row,:]·Wp[p,0:512] + bp[p] ).
// Grid (128,64): block = 128 rows x 64 cols; wave v: rows bx*128+v*32..+31.
__global__ __launch_bounds__(256) void xgates_mfma(
    const u16* __restrict__ x_tb,   // [16384][512]
    const u16* __restrict__ Wp,     // [4096][1536] (x-part = first 512)
    const float* __restrict__ bp,   // [4096]
    u16* __restrict__ Xg)           // [16384][4096]
{
    const int bx = blockIdx.x, by = blockIdx.y;
    const int tid = threadIdx.x;
    const int v = tid >> 6, l = tid & 63;
    const int l15 = l & 15, lh = l >> 4;

    const u16* ap = x_tb + ((size_t)(bx * 128 + v * 32 + l15)) * I_ + lh * 8;
    const u16* bpp = Wp + ((size_t)(by * 64 + l15)) * 1536 + lh * 8;

    f32x4 acc0[4] = {f32x4{0,0,0,0}, f32x4{0,0,0,0}, f32x4{0,0,0,0}, f32x4{0,0,0,0}};
    f32x4 acc1[4] = {f32x4{0,0,0,0}, f32x4{0,0,0,0}, f32x4{0,0,0,0}, f32x4{0,0,0,0}};

    #pragma unroll 4
    for (int kk = 0; kk < 16; ++kk) {
        bf16x8 a0 = *(const bf16x8*)(ap + kk * 32);
        bf16x8 a1 = *(const bf16x8*)(ap + (size_t)16 * I_ + kk * 32);
        #pragma unroll
        for (int nt = 0; nt < 4; ++nt) {
            bf16x8 bf = *(const bf16x8*)(bpp + (size_t)nt * 16 * 1536 + kk * 32);
            acc0[nt] = __builtin_amdgcn_mfma_f32_16x16x32_bf16(a0, bf, acc0[nt], 0, 0, 0);
            acc1[nt] = __builtin_amdgcn_mfma_f32_16x16x32_bf16(a1, bf, acc1[nt], 0, 0, 0);
        }
    }

    #pragma unroll
    for (int nt = 0; nt < 4; ++nt) {
        const int col = by * 64 + nt * 16 + l15;
        const float bo = bp[col];
        #pragma unroll
        for (int mtq = 0; mtq < 2; ++mtq) {
            #pragma unroll
            for (int rg = 0; rg < 4; ++rg) {
                const int row = bx * 128 + v * 32 + mtq * 16 + lh * 4 + rg;
                const float y = (mtq ? acc1[nt][rg] : acc0[nt][rg]) + bo;
                Xg[(size_t)row * 4096 + col] = f2bf(y);
            }
        }
    }
}

// ---------------- persistent LSTM scan (h-part only) ----------------
// 64 WGs x 256 thr (1 WG/CU via 128KB LDS). WG w owns units w*16..+15
// (packed rows w*64..+63), all 64 batches. Wave v: rows w*64+(v>>1)*32,
// batches (v&1)*32. h-part weights pinned in 256 VGPRs; c in 4 VGPRs/lane.
// h exchange: agent write-through u32 atomics + aux=17 bypass staging [r7].
__global__ __launch_bounds__(256, 1) void lstm_seq(
    const u16* __restrict__ Xg,      // [16384][4096] bf16 (x-gates + bias)
    const u16* __restrict__ Wp,      // [4096][1536]
    const float* __restrict__ rT,    // [257][64]
    const float* __restrict__ cx,    // (N,T,H) fp32
    u16* __restrict__ hA, u16* __restrict__ hB,   // [65536] bf16, fragment order
    float* __restrict__ c_final,     // [64][1024] fp32
    u16* __restrict__ hs,            // [64][256][1024] bf16 (in out2 region)
    u32* __restrict__ flags)         // [64*16]
{
    __shared__ u16 zls[N_ * H_];     // 128 KB
    const int w = blockIdx.x, tid = threadIdx.x;
    const int v = tid >> 6, l = tid & 63;
    const int l15 = l & 15, lh = l >> 4;
    const int mt = v >> 1, ntb = (v & 1) * 32;
    const int rowbase = w * 64 + mt * 32;

    // pin h-part weights: Wh[kk][mi] = row (rowbase+mi*16+l15), k = 512+kk*32+lh*8
    bf16x8 Wh[32][2];
    #pragma unroll
    for (int kk = 0; kk < 32; ++kk) {
        #pragma unroll
        for (int mi = 0; mi < 2; ++mi) {
            Wh[kk][mi] = *(const bf16x8*)(
                Wp + (size_t)(rowbase + mi * 16 + l15) * 1536 + I_ + kk * 32 + lh * 8);
        }
    }

    const int jb = (rowbase >> 2) + lh;      // unit (mi=0); mi=1 -> jb+4
    const int n0 = ntb + l15, n1 = n0 + 16;

    float cr0 = cx[(size_t)n0 * T_ * H_ + jb];
    float cr1 = cx[(size_t)n1 * T_ * H_ + jb];
    float cr2 = cx[(size_t)n0 * T_ * H_ + jb + 4];
    float cr3 = cx[(size_t)n1 * T_ * H_ + jb + 4];

    const int zoff = (ntb >> 4) * 32768 + l15 * 64 + lh * 16;

    for (int t = 0; t < T_; ++t) {
        const u16* hin = (t & 1) ? hB : hA;
        u16*       hout = (t & 1) ? hA : hB;

        if (t > 0) {
            if (tid < NWG) {
                while (__hip_atomic_load(flags + tid * 16, __ATOMIC_RELAXED,
                                         __HIP_MEMORY_SCOPE_AGENT) < (u32)t)
                    __builtin_amdgcn_s_sleep(1);
            }
            __syncthreads();
        }

        // stage hin -> LDS (linear copy, IC-bypass; 32 chunks of 1KB per wave)
        {
            const char* hinb = (const char*)hin;
            char* lb = (char*)zls;
            #pragma unroll
            for (int i = 0; i < 32; ++i) {
                const int cb = (v * 32 + i) * 1024;
                gload_lds16_bypass(hinb + cb + l * 16, lb + cb);
            }
        }

        f32x4 acc00 = {0.f, 0.f, 0.f, 0.f}, acc01 = {0.f, 0.f, 0.f, 0.f};
        f32x4 acc10 = {0.f, 0.f, 0.f, 0.f}, acc11 = {0.f, 0.f, 0.f, 0.f};
        const char* zp = (const char*)zls;

        // half A: chunks 0..15 of each wave in LDS (vmcnt: <=4 older hs stores
        // + 32 stages outstanding; wait 16 -> oldest 20 done -> chunks 0..15 ok)
        VMW(16);
        __syncthreads();
        #pragma unroll
        for (int kk = 0; kk < 16; ++kk) {
            bf16x8 b0 = *(const bf16x8*)(zp + zoff + kk * 1024);
            bf16x8 b1 = *(const bf16x8*)(zp + zoff + 32768 + kk * 1024);
            acc00 = __builtin_amdgcn_mfma_f32_16x16x32_bf16(Wh[kk][0], b0, acc00, 0, 0, 0);
            acc01 = __builtin_amdgcn_mfma_f32_16x16x32_bf16(Wh[kk][0], b1, acc01, 0, 0, 0);
            acc10 = __builtin_amdgcn_mfma_f32_16x16x32_bf16(Wh[kk][1], b0, acc10, 0, 0, 0);
            acc11 = __builtin_amdgcn_mfma_f32_16x16x32_bf16(Wh[kk][1], b1, acc11, 0, 0, 0);
        }

        VMW(0);
        __syncthreads();

        // x-gates + reset factors (issued here, hidden under half B's MFMAs;
        // sched_barrier in VMW pins them after the counted waits)
        const size_t xr0 = ((size_t)t * 64 + n0) * 4096;
        const size_t xr1 = ((size_t)t * 64 + n1) * 4096;
        const u16x4 xg00 = *(const u16x4*)(Xg + xr0 + 4 * jb);
        const u16x4 xg01 = *(const u16x4*)(Xg + xr1 + 4 * jb);
        const u16x4 xg10 = *(const u16x4*)(Xg + xr0 + 4 * (jb + 4));
        const u16x4 xg11 = *(const u16x4*)(Xg + xr1 + 4 * (jb + 4));
        const float rt0 = rT[t * 64 + n0],        rt1 = rT[t * 64 + n1];
        const float rn0 = rT[(t + 1) * 64 + n0],  rn1 = rT[(t + 1) * 64 + n1];

        // half B: chunks 16..31
        #pragma unroll
        for (int kk = 16; kk < 32; ++kk) {
            bf16x8 b0 = *(const bf16x8*)(zp + zoff + kk * 1024);
            bf16x8 b1 = *(const bf16x8*)(zp + zoff + 32768 + kk * 1024);
            acc00 = __builtin_amdgcn_mfma_f32_16x16x32_bf16(Wh[kk][0], b0, acc00, 0, 0, 0);
            acc01 = __builtin_amdgcn_mfma_f32_16x16x32_bf16(Wh[kk][0], b1, acc01, 0, 0, 0);
            acc10 = __builtin_amdgcn_mfma_f32_16x16x32_bf16(Wh[kk][1], b0, acc10, 0, 0, 0);
            acc11 = __builtin_amdgcn_mfma_f32_16x16x32_bf16(Wh[kk][1], b1, acc11, 0, 0, 0);
        }

        // epilogue: gates i,f,g,o = acc[0..3] + Xg[0..3]
        float hv00, hv01, hv10, hv11;
#define CELL(ACC, XG, CC, RT, HV) { \
        const float ig = ACC[0] + bf2f(XG[0]); \
        const float fg = ACC[1] + bf2f(XG[1]); \
        const float gg = ACC[2] + bf2f(XG[2]); \
        const float og = ACC[3] + bf2f(XG[3]); \
        const float cn = sigf(fg) * (CC * RT) + sigf(ig) * tanhfast(gg); \
        HV = sigf(og) * tanhfast(cn); \
        CC = cn; }
        CELL(acc00, xg00, cr0, rt0, hv00)
        CELL(acc01, xg01, cr1, rt1, hv01)
        CELL(acc10, xg10, cr2, rt0, hv10)
        CELL(acc11, xg11, cr3, rt1, hv11)
#undef CELL

        // h exchange: pair (jb, jb+1 via lane+16), u32 agent write-through
        const float s00 = hv00 * rn0, s01 = hv01 * rn1;
        const float s10 = hv10 * rn0, s11 = hv11 * rn1;
        const float p00 = __shfl_down(s00, 16), p01 = __shfl_down(s01, 16);
        const float p10 = __shfl_down(s10, 16), p11 = __shfl_down(s11, 16);
        if (!(lh & 1)) {
            const u32 v00 = (u32)f2bf(s00) | ((u32)f2bf(p00) << 16);
            const u32 v01 = (u32)f2bf(s01) | ((u32)f2bf(p01) << 16);
            const u32 v10 = (u32)f2bf(s10) | ((u32)f2bf(p10) << 16);
            const u32 v11 = (u32)f2bf(s11) | ((u32)f2bf(p11) << 16);
            __hip_atomic_store((u32*)(hout + hfrag_idx(n0, jb)), v00,
                               __ATOMIC_RELAXED, __HIP_MEMORY_SCOPE_AGENT);
            __hip_atomic_store((u32*)(hout + hfrag_idx(n1, jb)), v01,
                               __ATOMIC_RELAXED, __HIP_MEMORY_SCOPE_AGENT);
            __hip_atomic_store((u32*)(hout + hfrag_idx(n0, jb + 4)), v10,
                               __ATOMIC_RELAXED, __HIP_MEMORY_SCOPE_AGENT);
            __hip_atomic_store((u32*)(hout + hfrag_idx(n1, jb + 4)), v11,
                               __ATOMIC_RELAXED, __HIP_MEMORY_SCOPE_AGENT);
        }
        VMW(0);                      // release: h acked at IC
        __syncthreads();
        if (tid == 0)
            __hip_atomic_store(flags + w * 16, (u32)(t + 1),
                               __ATOMIC_RELAXED, __HIP_MEMORY_SCOPE_AGENT);

        // hs + c_final AFTER the release (drain during next step's poll)
        hs[((size_t)n0 * T_ + t) * H_ + jb]     = f2bf(hv00);
        hs[((size_t)n1 * T_ + t) * H_ + jb]     = f2bf(hv01);
        hs[((size_t)n0 * T_ + t) * H_ + jb + 4] = f2bf(hv10);
        hs[((size_t)n1 * T_ + t) * H_ + jb + 4] = f2bf(hv11);
        if (t == T_ - 1) {
            c_final[(size_t)n0 * H_ + jb]     = cr0;
            c_final[(size_t)n1 * H_ + jb]     = cr1;
            c_final[(size_t)n0 * H_ + jb + 4] = cr2;
            c_final[(size_t)n1 * H_ + jb + 4] = cr3;
        }
    }
}

// ---------------- output projection (MFMA GEMM + mish) ----------------
__global__ __launch_bounds__(256) void out_proj_mfma(
    const u16* __restrict__ hs, const u16* __restrict__ Wo,
    const float* __restrict__ b_out, float* __restrict__ out0)
{
    const int bx = blockIdx.x, by = blockIdx.y;
    const int tid = threadIdx.x;
    const int v = tid >> 6, l = tid & 63;
    const int l15 = l & 15, lh = l >> 4;

    const u16* ap = hs + ((size_t)(bx * 128 + v * 32 + l15)) * H_ + lh * 8;
    const u16* bpp = Wo + ((size_t)(by * 64 + l15)) * H_ + lh * 8;

    f32x4 acc0[4] = {f32x4{0,0,0,0}, f32x4{0,0,0,0}, f32x4{0,0,0,0}, f32x4{0,0,0,0}};
    f32x4 acc1[4] = {f32x4{0,0,0,0}, f32x4{0,0,0,0}, f32x4{0,0,0,0}, f32x4{0,0,0,0}};

    #pragma unroll 4
    for (int kk = 0; kk < 32; ++kk) {
        bf16x8 a0 = *(const bf16x8*)(ap + kk * 32);
        bf16x8 a1 = *(const bf16x8*)(ap + (size_t)16 * H_ + kk * 32);
        #pragma unroll
        for (int nt = 0; nt < 4; ++nt) {
            bf16x8 bf = *(const bf16x8*)(bpp + (size_t)nt * 16 * H_ + kk * 32);
            acc0[nt] = __builtin_amdgcn_mfma_f32_16x16x32_bf16(a0, bf, acc0[nt], 0, 0, 0);
            acc1[nt] = __builtin_amdgcn_mfma_f32_16x16x32_bf16(a1, bf, acc1[nt], 0, 0, 0);
        }
    }

    #pragma unroll
    for (int nt = 0; nt < 4; ++nt) {
        const int col = by * 64 + nt * 16 + l15;
        const float bo = b_out[col];
        #pragma unroll
        for (int mtq = 0; mtq < 2; ++mtq) {
            #pragma unroll
            for (int rg = 0; rg < 4; ++rg) {
                const int row = bx * 128 + v * 32 + mtq * 16 + lh * 4 + rg;
                const float y = (mtq ? acc1[nt][rg] : acc0[nt][rg]) + bo;
                const float sp = (y > 15.f) ? y : log1pf(__expf(y));
                out0[(size_t)row * H_ + col] = y * tanhfast(sp);
            }
        }
    }
}

__global__ __launch_bounds__(256) void bcast_h(
    const u16* __restrict__ hs, float* __restrict__ out1)
{
    const size_t total = (size_t)N_ * T_ * H_;
    for (size_t idx = (size_t)blockIdx.x * 256 + threadIdx.x; idx < total;
         idx += (size_t)gridDim.x * 256) {
        const int n = (int)(idx >> 18);
        const int j = (int)(idx & (H_ - 1));
        out1[idx] = bf2f(hs[((size_t)n * T_ + (T_ - 1)) * H_ + j]);
    }
}

__global__ __launch_bounds__(256) void bcast_c(
    const float* __restrict__ c_final, float* __restrict__ out2)
{
    const size_t total = (size_t)N_ * T_ * H_;
    for (size_t idx = (size_t)blockIdx.x * 256 + threadIdx.x; idx < total;
         idx += (size_t)gridDim.x * 256) {
        const int n = (int)(idx >> 18);
        const int j = (int)(idx & (H_ - 1));
        out2[idx] = c_final[n * H_ + j];
    }
}

extern "C" void kernel_launch(void* const* d_in, const int* in_sizes, int n_in,
                              void* d_out, int out_size, void* d_ws, size_t ws_size,
                              hipStream_t stream) {
    const float* x      = (const float*)d_in[0];
    const int*   is_ini = (const int*)  d_in[1];
    const float* hx     = (const float*)d_in[2];
    const float* cx     = (const float*)d_in[3];
    const float* W_ih   = (const float*)d_in[4];
    const float* W_hh   = (const float*)d_in[5];
    const float* b_ih   = (const float*)d_in[6];
    const float* b_hh   = (const float*)d_in[7];
    const float* W_out  = (const float*)d_in[8];
    const float* b_out  = (const float*)d_in[9];

    float* out0 = (float*)d_out;
    float* out1 = out0 + (size_t)N_ * T_ * H_;
    float* out2 = out1 + (size_t)N_ * T_ * H_;

    char* ws = (char*)d_ws;
    u16*   x_tb    = (u16*)  (ws + 0);          // 16,777,216
    u16*   Wp      = (u16*)  (ws + 16777216);   // 12,582,912
    float* bp      = (float*)(ws + 29360128);   // 16,384
    u16*   Wo_b    = (u16*)  (ws + 29376512);   // 2,097,152
    u16*   hA      = (u16*)  (ws + 31473664);   // 131,072
    u16*   hB      = (u16*)  (ws + 31604736);   // 131,072
    float* c_final = (float*)(ws + 31735808);   // 262,144
    float* rT      = (float*)(ws + 31997952);   // 65,792
    u32*   flags   = (u32*)  (ws + 32063744);   // 4,096

    u16* Xg = (u16*)out0;   // 134.2 MB scratch spanning out0+out1 (exact fit);
                            // consumed by lstm_seq, then overwritten by outputs
    u16* hs = (u16*)out2;   // 33.5 MB scratch inside out2 region

    hipMemsetAsync(flags, 0, NWG * 16 * sizeof(u32), stream);
    pack_weights<<<4096, 256, 0, stream>>>(W_ih, W_hh, b_ih, b_hh, Wp, bp);
    conv_x<<<dim3(T_, N_), 256, 0, stream>>>(x, x_tb);
    conv_wout<<<1024, 256, 0, stream>>>(W_out, Wo_b);
    init_rT<<<T_ + 1, 64, 0, stream>>>(is_ini, rT);
    init_h0<<<256, 256, 0, stream>>>(hx, is_ini, hA);

    xgates_mfma<<<dim3(128, 64), 256, 0, stream>>>(x_tb, Wp, bp, Xg);

    lstm_seq<<<NWG, 256, 0, stream>>>(Xg, Wp, rT, cx, hA, hB, c_final, hs, flags);

    out_proj_mfma<<<dim3(128, 16), 256, 0, stream>>>(hs, Wo_b, b_out, out0);
    bcast_h<<<2048, 256, 0, stream>>>(hs, out1);
    bcast_c<<<2048, 256, 0, stream>>>(c_final, out2);
}

// Round 10
// 1602.909 us; speedup vs baseline: 63.4465x; 1.3055x over previous
//
#include <hip/hip_runtime.h>
#include <math.h>

#define N_ 64
#define T_ 256
#define I_ 512
#define H_ 1024

typedef unsigned short u16;
typedef unsigned int u32;
typedef short bf16x8 __attribute__((ext_vector_type(8)));
typedef float f32x4 __attribute__((ext_vector_type(4)));
typedef u16 u16x4 __attribute__((ext_vector_type(4)));

__device__ __forceinline__ u16 f2bf(float f) {
    union { float f; unsigned int u; } x; x.f = f;
    unsigned int r = (x.u + 0x7FFFu + ((x.u >> 16) & 1u)) >> 16;
    return (u16)r;
}
__device__ __forceinline__ float bf2f(u16 u) {
    union { unsigned int u; float f; } x; x.u = ((unsigned int)u) << 16;
    return x.f;
}
__device__ __forceinline__ float sigf(float v) {
    return 1.0f / (1.0f + __expf(-v));
}
__device__ __forceinline__ float tanhfast(float x) {
    float e = __expf(2.0f * x);
    return 1.0f - 2.0f / (e + 1.0f);   // NaN-free at +-inf
}

// aux=17 = SC0|SC1: bypass L1/L2, read at IC (device coherence point) [proven r7/r9]
__device__ __forceinline__ void gload_lds16_bypass(const void* g, void* l) {
    __builtin_amdgcn_global_load_lds(
        (__attribute__((address_space(1))) void*)(g),
        (__attribute__((address_space(3))) void*)(l), 16, 0, 17);
}

#define VMW(Ncnt) do { \
    asm volatile("s_waitcnt vmcnt(" #Ncnt ")" ::: "memory"); \
    __builtin_amdgcn_sched_barrier(0); } while (0)

// Per-group h fragment layout (16 batches x 1024 units = 16384 u16 = 32KB):
// elem(nloc 0..15, unit j) = (j>>5)*512 + nloc*32 + (j&31). Chunk kk = k>>5 is 1KB.
__device__ __forceinline__ int hfrag16(int nloc, int j) {
    return ((j >> 5) << 9) + (nloc << 5) + (j & 31);
}

// ---------------- prep kernels ----------------

// Packed row rp = j*4+g : [W_ih[g*H+j][0:512] ; W_hh[g*H+j][0:1024]] bf16
__global__ __launch_bounds__(256) void pack_weights(
    const float* __restrict__ W_ih, const float* __restrict__ W_hh,
    const float* __restrict__ b_ih, const float* __restrict__ b_hh,
    u16* __restrict__ Wp, float* __restrict__ bp)
{
    const int rp = blockIdx.x;            // 0..4095
    const int j = rp >> 2, g = rp & 3;
    const int src = g * H_ + j;
    const float* wi = W_ih + (size_t)src * I_;
    const float* wh = W_hh + (size_t)src * H_;
    u16* dst = Wp + (size_t)rp * (I_ + H_);
    for (int k = threadIdx.x; k < I_; k += 256) dst[k] = f2bf(wi[k]);
    for (int k = threadIdx.x; k < H_; k += 256) dst[I_ + k] = f2bf(wh[k]);
    if (threadIdx.x == 0) bp[rp] = b_ih[src] + b_hh[src];
}

__global__ __launch_bounds__(256) void conv_x(
    const float* __restrict__ x, u16* __restrict__ x_tb)
{
    const int t = blockIdx.x, n = blockIdx.y;
    const float* s = x + ((size_t)n * T_ + t) * I_;
    u16* d = x_tb + ((size_t)t * N_ + n) * I_;
    for (int k = threadIdx.x; k < I_; k += 256) d[k] = f2bf(s[k]);
}

__global__ __launch_bounds__(256) void conv_wout(
    const float* __restrict__ W, u16* __restrict__ Wb)
{
    const size_t base = (size_t)blockIdx.x * 1024 + threadIdx.x;
    #pragma unroll
    for (int q = 0; q < 4; ++q) Wb[base + q * 256] = f2bf(W[base + q * 256]);
}

__global__ __launch_bounds__(64) void init_rT(
    const int* __restrict__ is_init, float* __restrict__ rT)
{
    const int t = blockIdx.x;    // 0..256
    const int n = threadIdx.x;   // 0..63
    float r = 1.0f;
    if (t < T_) r = (is_init[n * T_ + t] != 0) ? 0.0f : 1.0f;
    rT[t * 64 + n] = r;
}

// hbuf[group n>>4][parity 0] = bf16(hx[:,0]*r[0]) in per-group fragment layout
__global__ __launch_bounds__(256) void init_h0(
    const float* __restrict__ hx, const int* __restrict__ is_init,
    u16* __restrict__ hbuf)
{
    const int idx = blockIdx.x * 256 + threadIdx.x;   // 65536
    const int n = idx >> 10, j = idx & (H_ - 1);
    const float r = (is_init[n * T_] != 0) ? 0.0f : 1.0f;
    hbuf[(n >> 4) * 32768 + hfrag16(n & 15, j)] = f2bf(hx[(size_t)n * T_ * H_ + j] * r);
}

// ---------------- x-gate precompute (parallel MFMA GEMM) [proven r9] ----------
// Xg[row=(t*64+n)][p] = bf16( x_tb[row,:]·Wp[p,0:512] + bp[p] ).
__global__ __launch_bounds__(256) void xgates_mfma(
    const u16* __restrict__ x_tb,   // [16384][512]
    const u16* __restrict__ Wp,     // [4096][1536] (x-part = first 512)
    const float* __restrict__ bp,   // [4096]
    u16* __restrict__ Xg)           // [16384][4096]
{
    const int bx = blockIdx.x, by = blockIdx.y;
    const int tid = threadIdx.x;
    const int v = tid >> 6, l = tid & 63;
    const int l15 = l & 15, lh = l >> 4;

    const u16* ap = x_tb + ((size_t)(bx * 128 + v * 32 + l15)) * I_ + lh * 8;
    const u16* bpp = Wp + ((size_t)(by * 64 + l15)) * 1536 + lh * 8;

    f32x4 acc0[4] = {f32x4{0,0,0,0}, f32x4{0,0,0,0}, f32x4{0,0,0,0}, f32x4{0,0,0,0}};
    f32x4 acc1[4] = {f32x4{0,0,0,0}, f32x4{0,0,0,0}, f32x4{0,0,0,0}, f32x4{0,0,0,0}};

    #pragma unroll 4
    for (int kk = 0; kk < 16; ++kk) {
        bf16x8 a0 = *(const bf16x8*)(ap + kk * 32);
        bf16x8 a1 = *(const bf16x8*)(ap + (size_t)16 * I_ + kk * 32);
        #pragma unroll
        for (int nt = 0; nt < 4; ++nt) {
            bf16x8 bf = *(const bf16x8*)(bpp + (size_t)nt * 16 * 1536 + kk * 32);
            acc0[nt] = __builtin_amdgcn_mfma_f32_16x16x32_bf16(a0, bf, acc0[nt], 0, 0, 0);
            acc1[nt] = __builtin_amdgcn_mfma_f32_16x16x32_bf16(a1, bf, acc1[nt], 0, 0, 0);
        }
    }

    #pragma unroll
    for (int nt = 0; nt < 4; ++nt) {
        const int col = by * 64 + nt * 16 + l15;
        const float bo = bp[col];
        #pragma unroll
        for (int mtq = 0; mtq < 2; ++mtq) {
            #pragma unroll
            for (int rg = 0; rg < 4; ++rg) {
                const int row = bx * 128 + v * 32 + mtq * 16 + lh * 4 + rg;
                const float y = (mtq ? acc1[nt][rg] : acc0[nt][rg]) + bo;
                Xg[(size_t)row * 4096 + col] = f2bf(y);
            }
        }
    }
}

// ---------------- persistent LSTM scan: 32 unit-blocks x 4 batch-groups -------
// 128 WGs x 512 thr (8 waves). WG(u = bid&31, b = bid>>5) owns units u*32..+31
// for batches b*16..+15. Wave v: packed rows u*128+v*16..+15 (1 M-frag), all 16
// batches (1 N-frag). Wh pinned in 128 VGPR/lane; c in 1 VGPR/lane.
// Sync PER GROUP (32 WGs): IC flags; h exchange via write-through u32 + aux=17
// bypass staging of the group's 32 KB h into LDS. Groups fully decoupled.
__global__ __launch_bounds__(512, 1) void lstm_seq(
    const u16* __restrict__ Xg,      // [16384][4096] bf16 (x-gates + bias)
    const u16* __restrict__ Wp,      // [4096][1536]
    const float* __restrict__ rT,    // [257][64]
    const float* __restrict__ cx,    // (N,T,H) fp32
    u16* __restrict__ hbuf,          // [4][2][16384] bf16, per-group frag order
    float* __restrict__ c_final,     // [64][1024] fp32
    u16* __restrict__ hs,            // [64][256][1024] bf16 (in out2 region)
    u32* __restrict__ flags)         // [4][32] spaced x16 u32
{
    __shared__ u16 zls[16384];       // 32 KB: group h, fragment order
    const int tid = threadIdx.x;
    const int v = tid >> 6, l = tid & 63;
    const int l15 = l & 15, lh = l >> 4;
    const int u = blockIdx.x & 31, b = blockIdx.x >> 5;
    const int rowbase = u * 128 + v * 16;

    // pin h-part weights: Wh[kk] = packed row (rowbase + l15), k = 512 + kk*32 + lh*8
    bf16x8 Wh[32];
    #pragma unroll
    for (int kk = 0; kk < 32; ++kk)
        Wh[kk] = *(const bf16x8*)(
            Wp + (size_t)(rowbase + l15) * 1536 + I_ + kk * 32 + lh * 8);

    const int jb = u * 32 + v * 4 + lh;   // this lane's unit
    const int n = b * 16 + l15;           // this lane's batch

    float cr = cx[(size_t)n * T_ * H_ + jb];

    u16* gbase = hbuf + (size_t)b * 32768;
    u32* gflags = flags + b * 32 * 16;
    const int zoff = l15 * 64 + lh * 16;  // byte offset within 1KB chunk

    for (int t = 0; t < T_; ++t) {
        const u16* hin = gbase + (t & 1) * 16384;
        u16*       hout = gbase + ((t & 1) ^ 1) * 16384;

        if (t > 0) {
            if (tid < 32) {
                while (__hip_atomic_load(gflags + tid * 16, __ATOMIC_RELAXED,
                                         __HIP_MEMORY_SCOPE_AGENT) < (u32)t)
                    __builtin_amdgcn_s_sleep(1);
            }
            __syncthreads();
        }

        // stage group h (32 KB) -> LDS: wave v stages chunks v*4..v*4+3
        {
            const char* hinb = (const char*)hin;
            char* lb = (char*)zls;
            #pragma unroll
            for (int i = 0; i < 4; ++i) {
                const int cb = (v * 4 + i) * 1024;
                gload_lds16_bypass(hinb + cb + l * 16, lb + cb);
            }
        }

        // x-gates + reset factors (cached loads, latency hidden under staging)
        const u16x4 xg = *(const u16x4*)(Xg + ((size_t)t * 64 + n) * 4096 + 4 * jb);
        const float rt = rT[t * 64 + n];
        const float rn = rT[(t + 1) * 64 + n];

        VMW(0);
        __syncthreads();

        // h-part matmul: K=1024, A = pinned weights, B = LDS (conflict-free linear)
        f32x4 acc = {0.f, 0.f, 0.f, 0.f};
        const char* zp = (const char*)zls;
        #pragma unroll
        for (int kk = 0; kk < 32; ++kk) {
            bf16x8 bz = *(const bf16x8*)(zp + zoff + kk * 1024);
            acc = __builtin_amdgcn_mfma_f32_16x16x32_bf16(Wh[kk], bz, acc, 0, 0, 0);
        }

        // epilogue: 1 cell/lane; gates i,f,g,o = acc[0..3] + Xg
        const float ig = acc[0] + bf2f(xg[0]);
        const float fg = acc[1] + bf2f(xg[1]);
        const float gg = acc[2] + bf2f(xg[2]);
        const float og = acc[3] + bf2f(xg[3]);
        const float cn = sigf(fg) * (cr * rt) + sigf(ig) * tanhfast(gg);
        const float hv = sigf(og) * tanhfast(cn);
        cr = cn;

        // pair units (jb even, jb+1) via lane+16; u32 write-through to group buf
        const float hvp = __shfl_down(hv, 16);
        u32 hsv = 0;
        if (!(lh & 1)) {
            const u32 ho = (u32)f2bf(hv * rn) | ((u32)f2bf(hvp * rn) << 16);
            hsv = (u32)f2bf(hv) | ((u32)f2bf(hvp) << 16);
            __hip_atomic_store((u32*)(hout + (u << 9) + (l15 << 5) + (v << 2) + lh),
                               ho, __ATOMIC_RELAXED, __HIP_MEMORY_SCOPE_AGENT);
        }
        VMW(0);                      // release: h acked at IC
        __syncthreads();
        if (tid == 0)
            __hip_atomic_store(gflags + u * 16, (u32)(t + 1),
                               __ATOMIC_RELAXED, __HIP_MEMORY_SCOPE_AGENT);

        // hs (+ c_final at the end) AFTER the release — drains during next poll
        if (!(lh & 1))
            *(u32*)(hs + ((size_t)n * T_ + t) * H_ + jb) = hsv;
        if (t == T_ - 1)
            c_final[(size_t)n * H_ + jb] = cr;
    }
}

// ---------------- output projection (MFMA GEMM + mish) [proven r9] -----------
__global__ __launch_bounds__(256) void out_proj_mfma(
    const u16* __restrict__ hs, const u16* __restrict__ Wo,
    const float* __restrict__ b_out, float* __restrict__ out0)
{
    const int bx = blockIdx.x, by = blockIdx.y;
    const int tid = threadIdx.x;
    const int v = tid >> 6, l = tid & 63;
    const int l15 = l & 15, lh = l >> 4;

    const u16* ap = hs + ((size_t)(bx * 128 + v * 32 + l15)) * H_ + lh * 8;
    const u16* bpp = Wo + ((size_t)(by * 64 + l15)) * H_ + lh * 8;

    f32x4 acc0[4] = {f32x4{0,0,0,0}, f32x4{0,0,0,0}, f32x4{0,0,0,0}, f32x4{0,0,0,0}};
    f32x4 acc1[4] = {f32x4{0,0,0,0}, f32x4{0,0,0,0}, f32x4{0,0,0,0}, f32x4{0,0,0,0}};

    #pragma unroll 4
    for (int kk = 0; kk < 32; ++kk) {
        bf16x8 a0 = *(const bf16x8*)(ap + kk * 32);
        bf16x8 a1 = *(const bf16x8*)(ap + (size_t)16 * H_ + kk * 32);
        #pragma unroll
        for (int nt = 0; nt < 4; ++nt) {
            bf16x8 bf = *(const bf16x8*)(bpp + (size_t)nt * 16 * H_ + kk * 32);
            acc0[nt] = __builtin_amdgcn_mfma_f32_16x16x32_bf16(a0, bf, acc0[nt], 0, 0, 0);
            acc1[nt] = __builtin_amdgcn_mfma_f32_16x16x32_bf16(a1, bf, acc1[nt], 0, 0, 0);
        }
    }

    #pragma unroll
    for (int nt = 0; nt < 4; ++nt) {
        const int col = by * 64 + nt * 16 + l15;
        const float bo = b_out[col];
        #pragma unroll
        for (int mtq = 0; mtq < 2; ++mtq) {
            #pragma unroll
            for (int rg = 0; rg < 4; ++rg) {
                const int row = bx * 128 + v * 32 + mtq * 16 + lh * 4 + rg;
                const float y = (mtq ? acc1[nt][rg] : acc0[nt][rg]) + bo;
                const float sp = (y > 15.f) ? y : log1pf(__expf(y));
                out0[(size_t)row * H_ + col] = y * tanhfast(sp);
            }
        }
    }
}

__global__ __launch_bounds__(256) void bcast_h(
    const u16* __restrict__ hs, float* __restrict__ out1)
{
    const size_t total = (size_t)N_ * T_ * H_;
    for (size_t idx = (size_t)blockIdx.x * 256 + threadIdx.x; idx < total;
         idx += (size_t)gridDim.x * 256) {
        const int n = (int)(idx >> 18);
        const int j = (int)(idx & (H_ - 1));
        out1[idx] = bf2f(hs[((size_t)n * T_ + (T_ - 1)) * H_ + j]);
    }
}

__global__ __launch_bounds__(256) void bcast_c(
    const float* __restrict__ c_final, float* __restrict__ out2)
{
    const size_t total = (size_t)N_ * T_ * H_;
    for (size_t idx = (size_t)blockIdx.x * 256 + threadIdx.x; idx < total;
         idx += (size_t)gridDim.x * 256) {
        const int n = (int)(idx >> 18);
        const int j = (int)(idx & (H_ - 1));
        out2[idx] = c_final[n * H_ + j];
    }
}

extern "C" void kernel_launch(void* const* d_in, const int* in_sizes, int n_in,
                              void* d_out, int out_size, void* d_ws, size_t ws_size,
                              hipStream_t stream) {
    const float* x      = (const float*)d_in[0];
    const int*   is_ini = (const int*)  d_in[1];
    const float* hx     = (const float*)d_in[2];
    const float* cx     = (const float*)d_in[3];
    const float* W_ih   = (const float*)d_in[4];
    const float* W_hh   = (const float*)d_in[5];
    const float* b_ih   = (const float*)d_in[6];
    const float* b_hh   = (const float*)d_in[7];
    const float* W_out  = (const float*)d_in[8];
    const float* b_out  = (const float*)d_in[9];

    float* out0 = (float*)d_out;
    float* out1 = out0 + (size_t)N_ * T_ * H_;
    float* out2 = out1 + (size_t)N_ * T_ * H_;

    char* ws = (char*)d_ws;
    u16*   x_tb    = (u16*)  (ws + 0);          // 16,777,216
    u16*   Wp      = (u16*)  (ws + 16777216);   // 12,582,912
    float* bp      = (float*)(ws + 29360128);   // 16,384
    u16*   Wo_b    = (u16*)  (ws + 29376512);   // 2,097,152
    u16*   hbuf    = (u16*)  (ws + 31473664);   // 262,144  [4][2][16384] u16
    float* c_final = (float*)(ws + 31735808);   // 262,144
    float* rT      = (float*)(ws + 31997952);   // 65,792
    u32*   flags   = (u32*)  (ws + 32063744);   // 8,192    [4][32] x16-spaced

    u16* Xg = (u16*)out0;   // 134.2 MB scratch spanning out0+out1 (exact fit);
                            // consumed by lstm_seq, then overwritten by outputs
    u16* hs = (u16*)out2;   // 33.5 MB scratch inside out2 region

    hipMemsetAsync(flags, 0, 8192, stream);
    pack_weights<<<4096, 256, 0, stream>>>(W_ih, W_hh, b_ih, b_hh, Wp, bp);
    conv_x<<<dim3(T_, N_), 256, 0, stream>>>(x, x_tb);
    conv_wout<<<1024, 256, 0, stream>>>(W_out, Wo_b);
    init_rT<<<T_ + 1, 64, 0, stream>>>(is_ini, rT);
    init_h0<<<256, 256, 0, stream>>>(hx, is_ini, hbuf);

    xgates_mfma<<<dim3(128, 64), 256, 0, stream>>>(x_tb, Wp, bp, Xg);

    lstm_seq<<<128, 512, 0, stream>>>(Xg, Wp, rT, cx, hbuf, c_final, hs, flags);

    out_proj_mfma<<<dim3(128, 16), 256, 0, stream>>>(hs, Wo_b, b_out, out0);
    bcast_h<<<2048, 256, 0, stream>>>(hs, out1);
    bcast_c<<<2048, 256, 0, stream>>>(c_final, out2);
}

// Round 11
// 1489.645 us; speedup vs baseline: 68.2706x; 1.0760x over previous
//
#include <hip/hip_runtime.h>
#include <math.h>

#define N_ 64
#define T_ 256
#define I_ 512
#define H_ 1024

typedef unsigned short u16;
typedef unsigned int u32;
typedef short bf16x8 __attribute__((ext_vector_type(8)));
typedef float f32x4 __attribute__((ext_vector_type(4)));
typedef u16 u16x4 __attribute__((ext_vector_type(4)));

__device__ __forceinline__ u16 f2bf(float f) {
    union { float f; unsigned int u; } x; x.f = f;
    unsigned int r = (x.u + 0x7FFFu + ((x.u >> 16) & 1u)) >> 16;
    return (u16)r;
}
__device__ __forceinline__ float bf2f(u16 u) {
    union { unsigned int u; float f; } x; x.u = ((unsigned int)u) << 16;
    return x.f;
}
__device__ __forceinline__ float sigf(float v) {
    return 1.0f / (1.0f + __expf(-v));
}
__device__ __forceinline__ float tanhfast(float x) {
    float e = __expf(2.0f * x);
    return 1.0f - 2.0f / (e + 1.0f);   // NaN-free at +-inf
}

// aux=17 = SC0|SC1: bypass L1/L2, read at IC (device coherence point) [proven r7+]
__device__ __forceinline__ void gload_lds16_bypass(const void* g, void* l) {
    __builtin_amdgcn_global_load_lds(
        (__attribute__((address_space(1))) void*)(g),
        (__attribute__((address_space(3))) void*)(l), 16, 0, 17);
}
// cached variant (weights staging in GEMMs)
__device__ __forceinline__ void gload_lds16n(const void* g, void* l) {
    __builtin_amdgcn_global_load_lds(
        (__attribute__((address_space(1))) void*)(g),
        (__attribute__((address_space(3))) void*)(l), 16, 0, 0);
}

#define VMW(Ncnt) do { \
    asm volatile("s_waitcnt vmcnt(" #Ncnt ")" ::: "memory"); \
    __builtin_amdgcn_sched_barrier(0); } while (0)

// Per-group h fragment layout, LANE-MAJOR (conflict-free):
// elem(nloc 0..15, k 0..1023) = (k>>5)*512 + ((k>>3)&3)*128 + nloc*8 + (k&7).
// Wave read of chunk kk = contiguous 1KB at kk*1024 + lane*16 -> 0 conflicts.
__device__ __forceinline__ int hfrag16(int nloc, int k) {
    return ((k >> 5) << 9) + (((k >> 3) & 3) << 7) + (nloc << 3) + (k & 7);
}

// ---------------- prep kernels ----------------

// Packed row rp = j*4+g : [W_ih[g*H+j][0:512] ; W_hh[g*H+j][0:1024]] bf16
__global__ __launch_bounds__(256) void pack_weights(
    const float* __restrict__ W_ih, const float* __restrict__ W_hh,
    const float* __restrict__ b_ih, const float* __restrict__ b_hh,
    u16* __restrict__ Wp, float* __restrict__ bp)
{
    const int rp = blockIdx.x;            // 0..4095
    const int j = rp >> 2, g = rp & 3;
    const int src = g * H_ + j;
    const float* wi = W_ih + (size_t)src * I_;
    const float* wh = W_hh + (size_t)src * H_;
    u16* dst = Wp + (size_t)rp * (I_ + H_);
    for (int k = threadIdx.x; k < I_; k += 256) dst[k] = f2bf(wi[k]);
    for (int k = threadIdx.x; k < H_; k += 256) dst[I_ + k] = f2bf(wh[k]);
    if (threadIdx.x == 0) bp[rp] = b_ih[src] + b_hh[src];
}

__global__ __launch_bounds__(256) void conv_x(
    const float* __restrict__ x, u16* __restrict__ x_tb)
{
    const int t = blockIdx.x, n = blockIdx.y;
    const float* s = x + ((size_t)n * T_ + t) * I_;
    u16* d = x_tb + ((size_t)t * N_ + n) * I_;
    for (int k = threadIdx.x; k < I_; k += 256) d[k] = f2bf(s[k]);
}

__global__ __launch_bounds__(256) void conv_wout(
    const float* __restrict__ W, u16* __restrict__ Wb)
{
    const size_t base = (size_t)blockIdx.x * 1024 + threadIdx.x;
    #pragma unroll
    for (int q = 0; q < 4; ++q) Wb[base + q * 256] = f2bf(W[base + q * 256]);
}

__global__ __launch_bounds__(64) void init_rT(
    const int* __restrict__ is_init, float* __restrict__ rT)
{
    const int t = blockIdx.x;    // 0..256
    const int n = threadIdx.x;   // 0..63
    float r = 1.0f;
    if (t < T_) r = (is_init[n * T_ + t] != 0) ? 0.0f : 1.0f;
    rT[t * 64 + n] = r;
}

// hbuf[group n>>4][parity 0] = bf16(hx[:,0]*r[0]) in per-group fragment layout
__global__ __launch_bounds__(256) void init_h0(
    const float* __restrict__ hx, const int* __restrict__ is_init,
    u16* __restrict__ hbuf)
{
    const int idx = blockIdx.x * 256 + threadIdx.x;   // 65536
    const int n = idx >> 10, j = idx & (H_ - 1);
    const float r = (is_init[n * T_] != 0) ? 0.0f : 1.0f;
    hbuf[(n >> 4) * 32768 + hfrag16(n & 15, j)] = f2bf(hx[(size_t)n * T_ * H_ + j] * r);
}

// ---------------- x-gate precompute: 256x256-tile GEMM, LDS-dbuf B ----------
// Xg[row=(t*64+n)][p] = bf16( x_tb[row,:512]·Wp[p,:512] + bp[p] ).
// 512 thr / 8 waves; wave v: rows v*32..+31 (2 M-frags) x 256 cols (16 N-frags).
__global__ __launch_bounds__(512) __attribute__((amdgpu_waves_per_eu(2, 2)))
void xgates_mfma(
    const u16* __restrict__ x_tb,   // [16384][512]
    const u16* __restrict__ Wp,     // [4096][1536] (x-part = first 512)
    const float* __restrict__ bp,   // [4096]
    u16* __restrict__ Xg)           // [16384][4096]
{
    __shared__ u16 bls[2][8192];    // 2 x 16KB, lane-major per 16-col tile
    const int bx = blockIdx.x, by = blockIdx.y;
    const int tid = threadIdx.x;
    const int v = tid >> 6, l = tid & 63;
    const int l15 = l & 15, lh = l >> 4;
    const int rowb = bx * 256 + v * 32;
    const int colb = by * 256;

    const u16* ap0 = x_tb + (size_t)(rowb + l15) * I_ + lh * 8;
    const u16* ap1 = x_tb + (size_t)(rowb + 16 + l15) * I_ + lh * 8;
    const u16* bs0 = Wp + (size_t)(colb + (2 * v) * 16 + l15) * 1536 + lh * 8;
    const u16* bs1 = Wp + (size_t)(colb + (2 * v + 1) * 16 + l15) * 1536 + lh * 8;

    f32x4 acc[2][16];
    #pragma unroll
    for (int m = 0; m < 2; ++m)
        #pragma unroll
        for (int nt = 0; nt < 16; ++nt) acc[m][nt] = f32x4{0.f, 0.f, 0.f, 0.f};

#define STAGEX(S, B) do { \
    gload_lds16n(bs0 + (S) * 32, (char*)bls[B] + (2 * v) * 1024); \
    gload_lds16n(bs1 + (S) * 32, (char*)bls[B] + (2 * v + 1) * 1024); } while (0)

    STAGEX(0, 0);
    VMW(0); __syncthreads();
    int buf = 0;
    for (int s = 0; s < 16; ++s) {
        if (s < 15) STAGEX(s + 1, buf ^ 1);
        bf16x8 a0 = *(const bf16x8*)(ap0 + s * 32);
        bf16x8 a1 = *(const bf16x8*)(ap1 + s * 32);
        const char* bb = (const char*)bls[buf];
        #pragma unroll
        for (int nt = 0; nt < 16; ++nt) {
            bf16x8 bfr = *(const bf16x8*)(bb + nt * 1024 + l * 16);
            acc[0][nt] = __builtin_amdgcn_mfma_f32_16x16x32_bf16(a0, bfr, acc[0][nt], 0, 0, 0);
            acc[1][nt] = __builtin_amdgcn_mfma_f32_16x16x32_bf16(a1, bfr, acc[1][nt], 0, 0, 0);
        }
        VMW(0); __syncthreads();
        buf ^= 1;
    }
#undef STAGEX

    #pragma unroll
    for (int nt = 0; nt < 16; ++nt) {
        const int col = colb + nt * 16 + l15;
        const float bo = bp[col];
        #pragma unroll
        for (int mt = 0; mt < 2; ++mt)
            #pragma unroll
            for (int rg = 0; rg < 4; ++rg) {
                const int row = rowb + mt * 16 + lh * 4 + rg;
                Xg[(size_t)row * 4096 + col] = f2bf(acc[mt][nt][rg] + bo);
            }
    }
}

// ---------------- persistent LSTM scan: 32 unit-blocks x 4 batch-groups ------
// [proven r10 structure] + lane-major LDS layout + pinned-Wh register budget.
__global__ __launch_bounds__(512) __attribute__((amdgpu_waves_per_eu(2, 2)))
void lstm_seq(
    const u16* __restrict__ Xg,      // [16384][4096] bf16 (x-gates + bias)
    const u16* __restrict__ Wp,      // [4096][1536]
    const float* __restrict__ rT,    // [257][64]
    const float* __restrict__ cx,    // (N,T,H) fp32
    u16* __restrict__ hbuf,          // [4][2][16384] bf16, per-group frag order
    float* __restrict__ c_final,     // [64][1024] fp32
    u16* __restrict__ hs,            // [64][256][1024] bf16 (in out2 region)
    u32* __restrict__ flags)         // [4][32] spaced x16 u32
{
    __shared__ u16 zls[16384];       // 32 KB: group h, lane-major frag order
    const int tid = threadIdx.x;
    const int v = tid >> 6, l = tid & 63;
    const int l15 = l & 15, lh = l >> 4;
    const int u = blockIdx.x & 31, b = blockIdx.x >> 5;
    const int rowbase = u * 128 + v * 16;

    // pin h-part weights: Wh[kk] = packed row (rowbase + l15), k = 512+kk*32+lh*8
    bf16x8 Wh[32];
    #pragma unroll
    for (int kk = 0; kk < 32; ++kk)
        Wh[kk] = *(const bf16x8*)(
            Wp + (size_t)(rowbase + l15) * 1536 + I_ + kk * 32 + lh * 8);

    const int jb = u * 32 + v * 4 + lh;   // this lane's unit
    const int n = b * 16 + l15;           // this lane's batch

    float cr = cx[(size_t)n * T_ * H_ + jb];

    u16* gbase = hbuf + (size_t)b * 32768;
    u32* gflags = flags + b * 32 * 16;
    const int zoff = l * 16;              // lane-major: contiguous 1KB per wave read

    for (int t = 0; t < T_; ++t) {
        const u16* hin = gbase + (t & 1) * 16384;
        u16*       hout = gbase + ((t & 1) ^ 1) * 16384;

        if (t > 0) {
            if (tid < 32) {
                while (__hip_atomic_load(gflags + tid * 16, __ATOMIC_RELAXED,
                                         __HIP_MEMORY_SCOPE_AGENT) < (u32)t)
                    __builtin_amdgcn_s_sleep(1);
            }
            __syncthreads();
        }

        // stage group h (32 KB) -> LDS: wave v stages chunks v*4..v*4+3
        {
            const char* hinb = (const char*)hin;
            char* lb = (char*)zls;
            #pragma unroll
            for (int i = 0; i < 4; ++i) {
                const int cb = (v * 4 + i) * 1024;
                gload_lds16_bypass(hinb + cb + l * 16, lb + cb);
            }
        }

        // x-gates + reset factors (cached loads, latency hidden under staging)
        const u16x4 xg = *(const u16x4*)(Xg + ((size_t)t * 64 + n) * 4096 + 4 * jb);
        const float rt = rT[t * 64 + n];
        const float rn = rT[(t + 1) * 64 + n];

        VMW(0);
        __syncthreads();

        // h-part matmul: K=1024, A = pinned weights, B = LDS (conflict-free)
        f32x4 acc = {0.f, 0.f, 0.f, 0.f};
        const char* zp = (const char*)zls;
        #pragma unroll
        for (int kk = 0; kk < 32; ++kk) {
            bf16x8 bz = *(const bf16x8*)(zp + zoff + kk * 1024);
            acc = __builtin_amdgcn_mfma_f32_16x16x32_bf16(Wh[kk], bz, acc, 0, 0, 0);
        }

        // epilogue: 1 cell/lane; gates i,f,g,o = acc[0..3] + Xg
        const float ig = acc[0] + bf2f(xg[0]);
        const float fg = acc[1] + bf2f(xg[1]);
        const float gg = acc[2] + bf2f(xg[2]);
        const float og = acc[3] + bf2f(xg[3]);
        const float cn = sigf(fg) * (cr * rt) + sigf(ig) * tanhfast(gg);
        const float hv = sigf(og) * tanhfast(cn);
        cr = cn;

        // pair units (jb even, jb+1) via lane+16; u32 write-through to group buf
        const float hvp = __shfl_down(hv, 16);
        u32 hsv = 0;
        if (!(lh & 1)) {
            const u32 ho = (u32)f2bf(hv * rn) | ((u32)f2bf(hvp * rn) << 16);
            hsv = (u32)f2bf(hv) | ((u32)f2bf(hvp) << 16);
            __hip_atomic_store((u32*)(hout + hfrag16(l15, jb)), ho,
                               __ATOMIC_RELAXED, __HIP_MEMORY_SCOPE_AGENT);
        }
        VMW(0);                      // release: h acked at IC
        __syncthreads();
        if (tid == 0)
            __hip_atomic_store(gflags + u * 16, (u32)(t + 1),
                               __ATOMIC_RELAXED, __HIP_MEMORY_SCOPE_AGENT);

        // hs (+ c_final at the end) AFTER the release — drains during next poll
        if (!(lh & 1))
            *(u32*)(hs + ((size_t)n * T_ + t) * H_ + jb) = hsv;
        if (t == T_ - 1)
            c_final[(size_t)n * H_ + jb] = cr;
    }
}

// ---------------- output projection: 256x256-tile GEMM + mish ----------------
__global__ __launch_bounds__(512) __attribute__((amdgpu_waves_per_eu(2, 2)))
void out_proj_mfma(
    const u16* __restrict__ hs,     // [16384][1024]
    const u16* __restrict__ Wo,     // [1024][1024]
    const float* __restrict__ b_out,
    float* __restrict__ out0)       // [16384][1024]
{
    __shared__ u16 bls[2][8192];    // 2 x 16KB
    const int bx = blockIdx.x, by = blockIdx.y;
    const int tid = threadIdx.x;
    const int v = tid >> 6, l = tid & 63;
    const int l15 = l & 15, lh = l >> 4;
    const int rowb = bx * 256 + v * 32;
    const int colb = by * 256;

    const u16* ap0 = hs + (size_t)(rowb + l15) * H_ + lh * 8;
    const u16* ap1 = hs + (size_t)(rowb + 16 + l15) * H_ + lh * 8;
    const u16* bs0 = Wo + (size_t)(colb + (2 * v) * 16 + l15) * H_ + lh * 8;
    const u16* bs1 = Wo + (size_t)(colb + (2 * v + 1) * 16 + l15) * H_ + lh * 8;

    f32x4 acc[2][16];
    #pragma unroll
    for (int m = 0; m < 2; ++m)
        #pragma unroll
        for (int nt = 0; nt < 16; ++nt) acc[m][nt] = f32x4{0.f, 0.f, 0.f, 0.f};

#define STAGEO(S, B) do { \
    gload_lds16n(bs0 + (S) * 32, (char*)bls[B] + (2 * v) * 1024); \
    gload_lds16n(bs1 + (S) * 32, (char*)bls[B] + (2 * v + 1) * 1024); } while (0)

    STAGEO(0, 0);
    VMW(0); __syncthreads();
    int buf = 0;
    for (int s = 0; s < 32; ++s) {
        if (s < 31) STAGEO(s + 1, buf ^ 1);
        bf16x8 a0 = *(const bf16x8*)(ap0 + s * 32);
        bf16x8 a1 = *(const bf16x8*)(ap1 + s * 32);
        const char* bb = (const char*)bls[buf];
        #pragma unroll
        for (int nt = 0; nt < 16; ++nt) {
            bf16x8 bfr = *(const bf16x8*)(bb + nt * 1024 + l * 16);
            acc[0][nt] = __builtin_amdgcn_mfma_f32_16x16x32_bf16(a0, bfr, acc[0][nt], 0, 0, 0);
            acc[1][nt] = __builtin_amdgcn_mfma_f32_16x16x32_bf16(a1, bfr, acc[1][nt], 0, 0, 0);
        }
        VMW(0); __syncthreads();
        buf ^= 1;
    }
#undef STAGEO

    #pragma unroll
    for (int nt = 0; nt < 16; ++nt) {
        const int col = colb + nt * 16 + l15;
        const float bo = b_out[col];
        #pragma unroll
        for (int mt = 0; mt < 2; ++mt)
            #pragma unroll
            for (int rg = 0; rg < 4; ++rg) {
                const int row = rowb + mt * 16 + lh * 4 + rg;
                const float y = acc[mt][nt][rg] + bo;
                const float sp = (y > 15.f) ? y : log1pf(__expf(y));
                out0[(size_t)row * H_ + col] = y * tanhfast(sp);
            }
    }
}

// out1 = broadcast hs[:,255,:]  (hs in out2 region — MUST run before bcast_c)
__global__ __launch_bounds__(256) void bcast_h(
    const u16* __restrict__ hs, float* __restrict__ out1)
{
    const size_t total = (size_t)N_ * T_ * H_;
    for (size_t idx = (size_t)blockIdx.x * 256 + threadIdx.x; idx < total;
         idx += (size_t)gridDim.x * 256) {
        const int n = (int)(idx >> 18);
        const int j = (int)(idx & (H_ - 1));
        out1[idx] = bf2f(hs[((size_t)n * T_ + (T_ - 1)) * H_ + j]);
    }
}

__global__ __launch_bounds__(256) void bcast_c(
    const float* __restrict__ c_final, float* __restrict__ out2)
{
    const size_t total = (size_t)N_ * T_ * H_;
    for (size_t idx = (size_t)blockIdx.x * 256 + threadIdx.x; idx < total;
         idx += (size_t)gridDim.x * 256) {
        const int n = (int)(idx >> 18);
        const int j = (int)(idx & (H_ - 1));
        out2[idx] = c_final[n * H_ + j];
    }
}

extern "C" void kernel_launch(void* const* d_in, const int* in_sizes, int n_in,
                              void* d_out, int out_size, void* d_ws, size_t ws_size,
                              hipStream_t stream) {
    const float* x      = (const float*)d_in[0];
    const int*   is_ini = (const int*)  d_in[1];
    const float* hx     = (const float*)d_in[2];
    const float* cx     = (const float*)d_in[3];
    const float* W_ih   = (const float*)d_in[4];
    const float* W_hh   = (const float*)d_in[5];
    const float* b_ih   = (const float*)d_in[6];
    const float* b_hh   = (const float*)d_in[7];
    const float* W_out  = (const float*)d_in[8];
    const float* b_out  = (const float*)d_in[9];

    float* out0 = (float*)d_out;
    float* out1 = out0 + (size_t)N_ * T_ * H_;
    float* out2 = out1 + (size_t)N_ * T_ * H_;

    char* ws = (char*)d_ws;
    u16*   x_tb    = (u16*)  (ws + 0);          // 16,777,216
    u16*   Wp      = (u16*)  (ws + 16777216);   // 12,582,912
    float* bp      = (float*)(ws + 29360128);   // 16,384
    u16*   Wo_b    = (u16*)  (ws + 29376512);   // 2,097,152
    u16*   hbuf    = (u16*)  (ws + 31473664);   // 262,144  [4][2][16384] u16
    float* c_final = (float*)(ws + 31735808);   // 262,144
    float* rT      = (float*)(ws + 31997952);   // 65,792
    u32*   flags   = (u32*)  (ws + 32063744);   // 8,192    [4][32] x16-spaced

    u16* Xg = (u16*)out0;   // 134.2 MB scratch spanning out0+out1 (exact fit);
                            // consumed by lstm_seq, then overwritten by outputs
    u16* hs = (u16*)out2;   // 33.5 MB scratch inside out2 region

    hipMemsetAsync(flags, 0, 8192, stream);
    pack_weights<<<4096, 256, 0, stream>>>(W_ih, W_hh, b_ih, b_hh, Wp, bp);
    conv_x<<<dim3(T_, N_), 256, 0, stream>>>(x, x_tb);
    conv_wout<<<1024, 256, 0, stream>>>(W_out, Wo_b);
    init_rT<<<T_ + 1, 64, 0, stream>>>(is_ini, rT);
    init_h0<<<256, 256, 0, stream>>>(hx, is_ini, hbuf);

    xgates_mfma<<<dim3(64, 16), 512, 0, stream>>>(x_tb, Wp, bp, Xg);

    lstm_seq<<<128, 512, 0, stream>>>(Xg, Wp, rT, cx, hbuf, c_final, hs, flags);

    out_proj_mfma<<<dim3(64, 4), 512, 0, stream>>>(hs, Wo_b, b_out, out0);
    bcast_h<<<2048, 256, 0, stream>>>(hs, out1);
    bcast_c<<<2048, 256, 0, stream>>>(c_final, out2);
}